// Round 1
// baseline (33704.712 us; speedup 1.0000x reference)
//
#include <hip/hip_runtime.h>
#include <hip/hip_bf16.h>
#include <math.h>

// Problem constants
#define E_ 4
#define N_ 2048
#define D_ 256
#define H_ 8
#define F_ 2048
#define M_ 4096
#define L_ 3
#define GAMMA_ 0.1f
#define EPS_ 1e-5f

#define FLAG_ACC  1
#define FLAG_RELU 2

// ---------------------------------------------------------------------------
// Generic tiled f32 GEMM: C[M,N] = alpha * op(A) @ op(B) (+bias[N]) (+res[M,N])
// TA=0: A is [M,K] lda ; TA=1: A is [K,M] lda (i.e. use A^T)
// TB=0: B is [K,N] ldb ; TB=1: B is [N,K] ldb (i.e. use B^T)
// flags: FLAG_ACC -> C += v ; FLAG_RELU -> v = max(v,0)
// ---------------------------------------------------------------------------
template<bool TA, bool TB>
__global__ void gemm_kernel(const float* __restrict__ A, const float* __restrict__ B,
                            float* __restrict__ C, int M, int N, int K,
                            int lda, int ldb, int ldc, float alpha,
                            const float* __restrict__ bias,
                            const float* __restrict__ res, int flags) {
    __shared__ float As[16][64 + 1];
    __shared__ float Bs[16][64 + 1];
    int tx = threadIdx.x, ty = threadIdx.y;
    int tid = ty * 16 + tx;
    int bm = blockIdx.y * 64, bn = blockIdx.x * 64;
    float acc[4][4] = {};

    for (int k0 = 0; k0 < K; k0 += 16) {
        for (int i = tid; i < 64 * 16; i += 256) {
            int m, k;
            if (TA) { m = i & 63; k = i >> 6; }
            else    { m = i >> 4; k = i & 15; }
            int gm = bm + m, gk = k0 + k;
            float v = 0.f;
            if (gm < M && gk < K)
                v = TA ? A[(long)gk * lda + gm] : A[(long)gm * lda + gk];
            As[k][m] = v;
        }
        for (int i = tid; i < 64 * 16; i += 256) {
            int n, k;
            if (TB) { n = i >> 4; k = i & 15; }
            else    { n = i & 63; k = i >> 6; }
            int gn = bn + n, gk = k0 + k;
            float v = 0.f;
            if (gn < N && gk < K)
                v = TB ? B[(long)gn * ldb + gk] : B[(long)gk * ldb + gn];
            Bs[k][n] = v;
        }
        __syncthreads();
        #pragma unroll
        for (int k = 0; k < 16; ++k) {
            float a[4], b[4];
            #pragma unroll
            for (int i = 0; i < 4; ++i) a[i] = As[k][ty * 4 + i];
            #pragma unroll
            for (int j = 0; j < 4; ++j) b[j] = Bs[k][tx * 4 + j];
            #pragma unroll
            for (int i = 0; i < 4; ++i)
                #pragma unroll
                for (int j = 0; j < 4; ++j)
                    acc[i][j] = fmaf(a[i], b[j], acc[i][j]);
        }
        __syncthreads();
    }

    #pragma unroll
    for (int i = 0; i < 4; ++i) {
        int row = bm + ty * 4 + i;
        if (row >= M) continue;
        #pragma unroll
        for (int j = 0; j < 4; ++j) {
            int col = bn + tx * 4 + j;
            if (col >= N) continue;
            float v = alpha * acc[i][j];
            if (bias) v += bias[col];
            if (res)  v += res[(long)row * ldc + col];
            if (flags & FLAG_RELU) v = fmaxf(v, 0.f);
            long idx = (long)row * ldc + col;
            if (flags & FLAG_ACC) C[idx] += v;
            else                  C[idx] = v;
        }
    }
}

// Row softmax in-place; cols <= 6144. One block (256 threads) per row.
__global__ void softmax_rows(float* __restrict__ S, int cols) {
    __shared__ float buf[6144];
    __shared__ float red[256];
    int row = blockIdx.x, t = threadIdx.x;
    float* r = S + (long)row * cols;
    float lmax = -INFINITY;
    for (int c = t; c < cols; c += 256) { float v = r[c]; buf[c] = v; lmax = fmaxf(lmax, v); }
    red[t] = lmax; __syncthreads();
    for (int s = 128; s > 0; s >>= 1) { if (t < s) red[t] = fmaxf(red[t], red[t + s]); __syncthreads(); }
    float m = red[0]; __syncthreads();
    float lsum = 0.f;
    for (int c = t; c < cols; c += 256) { float e = expf(buf[c] - m); buf[c] = e; lsum += e; }
    red[t] = lsum; __syncthreads();
    for (int s = 128; s > 0; s >>= 1) { if (t < s) red[t] += red[t + s]; __syncthreads(); }
    float inv = 1.0f / red[0];
    for (int c = t; c < cols; c += 256) r[c] = buf[c] * inv;
}

// LayerNorm over D=256, one block (256 threads) per row. out = LN(X)*g + b
__global__ void layernorm_rows(const float* __restrict__ X, const float* __restrict__ g,
                               const float* __restrict__ b, float* __restrict__ out) {
    __shared__ float red[256];
    int row = blockIdx.x, t = threadIdx.x;
    float v = X[(long)row * 256 + t];
    red[t] = v; __syncthreads();
    for (int s = 128; s > 0; s >>= 1) { if (t < s) red[t] += red[t + s]; __syncthreads(); }
    float mu = red[0] * (1.0f / 256.0f); __syncthreads();
    float d = v - mu;
    red[t] = d * d; __syncthreads();
    for (int s = 128; s > 0; s >>= 1) { if (t < s) red[t] += red[t + s]; __syncthreads(); }
    float var = red[0] * (1.0f / 256.0f);
    out[(long)row * 256 + t] = d * rsqrtf(var + EPS_) * g[t] + b[t];
}

// Build ctx[3N, D] = concat(tokens[j], j != e)
__global__ void build_ctx(const float* __restrict__ tokens, float* __restrict__ ctx, int e) {
    long i = (long)blockIdx.x * 256 + threadIdx.x;
    if (i < (long)3 * N_ * D_) {
        int r = (int)(i >> 8);          // row in [0, 3N)
        int d = (int)(i & 255);
        int c = r >> 11;                // which of 3 chunks (N=2048)
        int rn = r & 2047;
        int j = (c < e) ? c : c + 1;
        ctx[i] = tokens[((long)j * N_ + rn) * D_ + d];
    }
}

// new_mem = (1-gamma)*mem + gamma*updsum
__global__ void mem_update(const float* __restrict__ mem, const float* __restrict__ upd,
                           float* __restrict__ out) {
    long i = (long)blockIdx.x * 256 + threadIdx.x;
    if (i < (long)L_ * M_ * D_) out[i] = (1.0f - GAMMA_) * mem[i] + GAMMA_ * upd[i];
}

// Partial pooled mean: grid (E, 16), 256 threads (one per d)
__global__ void pool_partial(const float* __restrict__ xf, float* __restrict__ pooled) {
    int e = blockIdx.x, chunk = blockIdx.y, t = threadIdx.x;
    float s = 0.f;
    int n0 = chunk * (N_ / 16);
    for (int n = n0; n < n0 + N_ / 16; ++n)
        s += xf[((long)e * N_ + n) * D_ + t];
    atomicAdd(&pooled[e * D_ + t], s * (1.0f / (float)N_));
}

// Gate: logits[e] = dot(pooled[e], gg) ; softmax over E=4
__global__ void gate_kernel(const float* __restrict__ pooled, const float* __restrict__ gg,
                            float* __restrict__ out_gate, float* __restrict__ ws_gate) {
    __shared__ float red[256];
    __shared__ float logits[4];
    int t = threadIdx.x;
    for (int e = 0; e < 4; ++e) {
        red[t] = pooled[e * 256 + t] * gg[t];
        __syncthreads();
        for (int s = 128; s > 0; s >>= 1) { if (t < s) red[t] += red[t + s]; __syncthreads(); }
        if (t == 0) logits[e] = red[0];
        __syncthreads();
    }
    if (t == 0) {
        float m = fmaxf(fmaxf(logits[0], logits[1]), fmaxf(logits[2], logits[3]));
        float g[4]; float s = 0.f;
        for (int e = 0; e < 4; ++e) { g[e] = expf(logits[e] - m); s += g[e]; }
        for (int e = 0; e < 4; ++e) {
            float w = g[e] / s;
            out_gate[e] = w;
            ws_gate[e] = w;
        }
    }
}

// fused[n,d] = sum_e g[e]*xf[e,n,d]
__global__ void fuse_kernel(const float* __restrict__ xf, const float* __restrict__ g4,
                            float* __restrict__ out) {
    long i = (long)blockIdx.x * 256 + threadIdx.x;
    const long ND = (long)N_ * D_;
    if (i < ND) {
        out[i] = g4[0] * xf[i] + g4[1] * xf[ND + i] + g4[2] * xf[2 * ND + i] + g4[3] * xf[3 * ND + i];
    }
}

// ---------------------------------------------------------------------------

static void launch_gemm(bool ta, bool tb, const float* A, const float* B, float* C,
                        int M, int N, int K, int lda, int ldb, int ldc, float alpha,
                        const float* bias, const float* res, int flags, hipStream_t stream) {
    dim3 grid((N + 63) / 64, (M + 63) / 64, 1), block(16, 16, 1);
    if (!ta && !tb)
        gemm_kernel<false, false><<<grid, block, 0, stream>>>(A, B, C, M, N, K, lda, ldb, ldc, alpha, bias, res, flags);
    else if (!ta && tb)
        gemm_kernel<false, true><<<grid, block, 0, stream>>>(A, B, C, M, N, K, lda, ldb, ldc, alpha, bias, res, flags);
    else if (ta && !tb)
        gemm_kernel<true, false><<<grid, block, 0, stream>>>(A, B, C, M, N, K, lda, ldb, ldc, alpha, bias, res, flags);
    else
        gemm_kernel<true, true><<<grid, block, 0, stream>>>(A, B, C, M, N, K, lda, ldb, ldc, alpha, bias, res, flags);
}

extern "C" void kernel_launch(void* const* d_in, const int* in_sizes, int n_in,
                              void* d_out, int out_size, void* d_ws, size_t ws_size,
                              hipStream_t stream) {
    const float* tokens    = (const float*)d_in[0];
    const float* memories  = (const float*)d_in[1];
    const float* in_proj_w = (const float*)d_in[2];
    const float* in_proj_b = (const float*)d_in[3];
    const float* out_w     = (const float*)d_in[4];
    const float* out_b     = (const float*)d_in[5];
    const float* lin1_w    = (const float*)d_in[6];
    const float* lin1_b    = (const float*)d_in[7];
    const float* lin2_w    = (const float*)d_in[8];
    const float* lin2_b    = (const float*)d_in[9];
    const float* ln1_w     = (const float*)d_in[10];
    const float* ln1_b     = (const float*)d_in[11];
    const float* ln2_w     = (const float*)d_in[12];
    const float* ln2_b     = (const float*)d_in[13];
    const float* agg_w     = (const float*)d_in[14];
    const float* agg_b     = (const float*)d_in[15];
    const float* gg        = (const float*)d_in[16];

    // Workspace layout (floats). Total ~28.84M floats ~= 115.4 MB.
    float* ws      = (float*)d_ws;
    float* xfinal  = ws;                      // E*N*D        = 2,097,152
    float* ctx     = xfinal + 2097152;        // 3N*D         = 1,572,864
    float* S       = ctx + 1572864;           // N*6144       = 12,582,912
    float* qkv     = S + 12582912;            // N*768        = 1,572,864
    float* x0      = qkv + 1572864;           // N*D          = 524,288
    float* x1      = x0 + 524288;             // N*D          = 524,288
    float* ybuf    = x1 + 524288;             // N*D          = 524,288
    float* obuf    = ybuf + 524288;           // N*D          = 524,288
    float* hid     = obuf + 524288;           // N*F          = 4,194,304
    float* retcat  = hid + 4194304;           // N*3D         = 1,572,864
    float* updsum  = retcat + 1572864;        // L*M*D        = 3,145,728
    float* pooled  = updsum + 3145728;        // E*D          = 1,024
    float* gatebuf = pooled + 1024;           // 4

    float* out_fused = (float*)d_out;               // N*D
    float* out_gate  = out_fused + (long)N_ * D_;   // E
    float* out_mem   = out_gate + E_;               // L*M*D

    const float scaleD = 1.0f / 16.0f;              // 1/sqrt(256)
    const float scaleH = 1.0f / sqrtf(32.0f);       // 1/sqrt(hd)

    hipMemsetAsync(updsum, 0, (size_t)3145728 * sizeof(float), stream);
    hipMemsetAsync(pooled, 0, (size_t)1024 * sizeof(float), stream);

    for (int e = 0; e < E_; ++e) {
        const float* tok = tokens + (long)e * N_ * D_;
        float* x2 = xfinal + (long)e * N_ * D_;

        // --- cross-expert attention ---
        build_ctx<<<dim3((3 * N_ * D_ + 255) / 256), dim3(256), 0, stream>>>(tokens, ctx, e);
        // S = tok @ ctx^T * scale   [N, 3N]
        launch_gemm(false, true, tok, ctx, S, N_, 3 * N_, D_, D_, D_, 3 * N_, scaleD,
                    nullptr, nullptr, 0, stream);
        softmax_rows<<<dim3(N_), dim3(256), 0, stream>>>(S, 3 * N_);
        // x0 = tok + P @ ctx
        launch_gemm(false, false, S, ctx, x0, N_, D_, 3 * N_, 3 * N_, D_, D_, 1.0f,
                    nullptr, tok, 0, stream);

        // --- MHA ---
        // qkv = x0 @ Wqkv^T + b    [N, 3D]
        launch_gemm(false, true, x0, in_proj_w + (long)e * 3 * D_ * D_, qkv,
                    N_, 3 * D_, D_, D_, D_, 3 * D_, 1.0f,
                    in_proj_b + (long)e * 3 * D_, nullptr, 0, stream);
        for (int h = 0; h < H_; ++h) {
            const int hd = D_ / H_; // 32
            // S = q_h @ k_h^T / sqrt(hd)   [N, N]
            launch_gemm(false, true, qkv + h * hd, qkv + D_ + h * hd, S,
                        N_, N_, hd, 3 * D_, 3 * D_, N_, scaleH, nullptr, nullptr, 0, stream);
            softmax_rows<<<dim3(N_), dim3(256), 0, stream>>>(S, N_);
            // o_h = P @ v_h   [N, hd] -> obuf[:, h*hd:]
            launch_gemm(false, false, S, qkv + 2 * D_ + h * hd, obuf + h * hd,
                        N_, hd, N_, N_, 3 * D_, D_, 1.0f, nullptr, nullptr, 0, stream);
        }
        // ybuf = x0 + obuf @ Wo^T + bo
        launch_gemm(false, true, obuf, out_w + (long)e * D_ * D_, ybuf,
                    N_, D_, D_, D_, D_, D_, 1.0f,
                    out_b + (long)e * D_, x0, 0, stream);
        // x1 = LN1(ybuf)
        layernorm_rows<<<dim3(N_), dim3(256), 0, stream>>>(ybuf, ln1_w + (long)e * D_,
                                                           ln1_b + (long)e * D_, x1);

        // --- FFN ---
        launch_gemm(false, true, x1, lin1_w + (long)e * F_ * D_, hid,
                    N_, F_, D_, D_, D_, F_, 1.0f,
                    lin1_b + (long)e * F_, nullptr, FLAG_RELU, stream);
        launch_gemm(false, true, hid, lin2_w + (long)e * D_ * F_, ybuf,
                    N_, D_, F_, F_, F_, D_, 1.0f,
                    lin2_b + (long)e * D_, x1, 0, stream);
        // x2 = LN2(ybuf)  (stored into xfinal[e])
        layernorm_rows<<<dim3(N_), dim3(256), 0, stream>>>(ybuf, ln2_w + (long)e * D_,
                                                           ln2_b + (long)e * D_, x2);

        // --- memory read/write ---
        for (int l = 0; l < L_; ++l) {
            const float* mem_l = memories + (long)l * M_ * D_;
            // S = x2 @ mem^T * scale   [N, M]
            launch_gemm(false, true, x2, mem_l, S, N_, M_, D_, D_, D_, M_, scaleD,
                        nullptr, nullptr, 0, stream);
            softmax_rows<<<dim3(N_), dim3(256), 0, stream>>>(S, M_);
            // retcat[:, l*D:(l+1)*D] = P @ mem
            launch_gemm(false, false, S, mem_l, retcat + l * D_,
                        N_, D_, M_, M_, D_, L_ * D_, 1.0f, nullptr, nullptr, 0, stream);
            // updsum[l] += P^T @ x2   [M, D]
            launch_gemm(true, false, S, x2, updsum + (long)l * M_ * D_,
                        M_, D_, N_, M_, D_, D_, 1.0f, nullptr, nullptr, FLAG_ACC, stream);
        }
        // xfinal[e] = x2 + retcat @ agg_w^T + agg_b   (in place, res == C)
        launch_gemm(false, true, retcat, agg_w, x2,
                    N_, D_, L_ * D_, L_ * D_, L_ * D_, D_, 1.0f,
                    agg_b, x2, 0, stream);
    }

    // new memories
    mem_update<<<dim3((L_ * M_ * D_ + 255) / 256), dim3(256), 0, stream>>>(memories, updsum, out_mem);

    // pooled mean + gate + fused
    pool_partial<<<dim3(E_, 16), dim3(256), 0, stream>>>(xfinal, pooled);
    gate_kernel<<<dim3(1), dim3(256), 0, stream>>>(pooled, gg, out_gate, gatebuf);
    fuse_kernel<<<dim3((N_ * D_ + 255) / 256), dim3(256), 0, stream>>>(xfinal, gatebuf, out_fused);
}

// Round 2
// 4299.424 us; speedup vs baseline: 7.8394x; 7.8394x over previous
//
#include <hip/hip_runtime.h>
#include <hip/hip_bf16.h>
#include <math.h>

// Problem constants
#define E_ 4
#define N_ 2048
#define D_ 256
#define H_ 8
#define F_ 2048
#define M_ 4096
#define L_ 3
#define GAMMA_ 0.1f
#define EPS_ 1e-5f

#define GF_ATOMIC 1
#define GF_RELU   2

typedef __attribute__((ext_vector_type(8))) short  sh8;
typedef __attribute__((ext_vector_type(4))) float  fx4;
typedef __hip_bfloat16 bf16;

__device__ inline void gload_lds16(const void* g, void* l) {
    __builtin_amdgcn_global_load_lds((const __attribute__((address_space(1))) void*)g,
                                     (__attribute__((address_space(3))) void*)l, 16, 0, 0);
}

// ---------------------------------------------------------------------------
// bf16 MFMA GEMM: C[M,N] (f32 and/or bf16) = alpha * A @ Bt^T (+bias)(+res)
// A: [M,K] row-major bf16, lda ; Bt: [N,K] row-major bf16, ldb
// Split-K over blockIdx.z (chunk Kc); GF_ATOMIC -> atomicAdd into C (f32).
// M must be a multiple of 128; K a multiple of 32; N,K bounds-checked.
// ---------------------------------------------------------------------------
__global__ __launch_bounds__(256, 2)
void gemm_bf16(const bf16* __restrict__ A, int lda,
               const bf16* __restrict__ Bt, int ldb,
               float* C, int ldc, bf16* Cbf,
               int M, int N, int K, int Kc,
               float alpha, const float* __restrict__ bias,
               const float* res, int ldres, int flags,
               const bf16* __restrict__ zerobuf)
{
    __shared__ char smem[32768];
    char* sA = smem;
    char* sB = smem + 16384;
    const int tid  = threadIdx.x;
    const int lane = tid & 63;
    const int wid  = tid >> 6;
    const int wm   = wid >> 1, wn = wid & 1;
    const int bm   = blockIdx.y * 128, bn = blockIdx.x * 128;

    const int kbeg = blockIdx.z * Kc;
    const int kend = min(K, kbeg + Kc);

    fx4 acc[4][4] = {};

    for (int k0 = kbeg; k0 < kend; k0 += 64) {
        // stage A tile [128][64] bf16 -> LDS (linear dest, pre-swizzled source)
        #pragma unroll
        for (int i = 0; i < 4; ++i) {
            int id  = (wid * 4 + i) * 64 + lane;     // chunk id 0..1023
            int row = id >> 3;
            int c   = (id & 7) ^ (row & 7);          // source chunk (inverse swizzle)
            int gk  = k0 + c * 8;
            const bf16* gp = (gk < kend) ? (A + (long)(bm + row) * lda + gk) : zerobuf;
            gload_lds16(gp, sA + (wid * 4 + i) * 1024);
        }
        // stage Bt tile [128][64]
        #pragma unroll
        for (int i = 0; i < 4; ++i) {
            int id  = (wid * 4 + i) * 64 + lane;
            int row = id >> 3;
            int c   = (id & 7) ^ (row & 7);
            int gk  = k0 + c * 8;
            const bf16* gp = (gk < kend && bn + row < N) ? (Bt + (long)(bn + row) * ldb + gk)
                                                         : zerobuf;
            gload_lds16(gp, sB + (wid * 4 + i) * 1024);
        }
        asm volatile("s_waitcnt vmcnt(0)" ::: "memory");
        __syncthreads();

        #pragma unroll
        for (int kk = 0; kk < 2; ++kk) {
            const int ko = kk * 32 + (lane >> 4) * 8;   // k within tile
            sh8 af[4], bfr[4];
            #pragma unroll
            for (int i = 0; i < 4; ++i) {
                int row = wm * 64 + i * 16 + (lane & 15);
                int off = (row * 128 + ko * 2) ^ ((row & 7) << 4);
                af[i] = *(const sh8*)(sA + off);
            }
            #pragma unroll
            for (int j = 0; j < 4; ++j) {
                int row = wn * 64 + j * 16 + (lane & 15);
                int off = (row * 128 + ko * 2) ^ ((row & 7) << 4);
                bfr[j] = *(const sh8*)(sB + off);
            }
            #pragma unroll
            for (int i = 0; i < 4; ++i)
                #pragma unroll
                for (int j = 0; j < 4; ++j)
                    acc[i][j] = __builtin_amdgcn_mfma_f32_16x16x32_bf16(af[i], bfr[j], acc[i][j], 0, 0, 0);
        }
        __syncthreads();
    }

    const bool z0 = (blockIdx.z == 0);
    #pragma unroll
    for (int j = 0; j < 4; ++j) {
        int col = bn + wn * 64 + j * 16 + (lane & 15);
        if (col >= N) continue;
        #pragma unroll
        for (int i = 0; i < 4; ++i) {
            #pragma unroll
            for (int r = 0; r < 4; ++r) {
                int row = bm + wm * 64 + i * 16 + (lane >> 4) * 4 + r;
                float v = alpha * acc[i][j][r];
                if (z0) {
                    if (bias) v += bias[col];
                    if (res)  v += res[(long)row * ldres + col];
                }
                if (flags & GF_RELU) v = fmaxf(v, 0.f);
                long idx = (long)row * ldc + col;
                if (flags & GF_ATOMIC) atomicAdd(&C[idx], v);
                else {
                    if (C)   C[idx] = v;
                    if (Cbf) Cbf[idx] = __float2bfloat16(v);
                }
            }
        }
    }
}

// Row softmax: reads f32 S, writes bf16 P. One block (256 thr) per row, cols<=6144.
__global__ void softmax_rows(const float* __restrict__ S, bf16* __restrict__ P, int cols) {
    __shared__ float buf[6144];
    __shared__ float red[256];
    int row = blockIdx.x, t = threadIdx.x;
    const float* r = S + (long)row * cols;
    float lmax = -INFINITY;
    for (int c = t; c < cols; c += 256) { float v = r[c]; buf[c] = v; lmax = fmaxf(lmax, v); }
    red[t] = lmax; __syncthreads();
    for (int s = 128; s > 0; s >>= 1) { if (t < s) red[t] = fmaxf(red[t], red[t + s]); __syncthreads(); }
    float m = red[0]; __syncthreads();
    float lsum = 0.f;
    for (int c = t; c < cols; c += 256) { float e = __expf(buf[c] - m); buf[c] = e; lsum += e; }
    red[t] = lsum; __syncthreads();
    for (int s = 128; s > 0; s >>= 1) { if (t < s) red[t] += red[t + s]; __syncthreads(); }
    float inv = 1.0f / red[0];
    bf16* o = P + (long)row * cols;
    for (int c = t; c < cols; c += 256) o[c] = __float2bfloat16(buf[c] * inv);
}

// LayerNorm over D=256 -> f32 + bf16 outputs
__global__ void layernorm_rows(const float* __restrict__ X, const float* __restrict__ g,
                               const float* __restrict__ b, float* __restrict__ out,
                               bf16* __restrict__ outbf) {
    __shared__ float red[256];
    int row = blockIdx.x, t = threadIdx.x;
    float v = X[(long)row * 256 + t];
    red[t] = v; __syncthreads();
    for (int s = 128; s > 0; s >>= 1) { if (t < s) red[t] += red[t + s]; __syncthreads(); }
    float mu = red[0] * (1.0f / 256.0f); __syncthreads();
    float d = v - mu;
    red[t] = d * d; __syncthreads();
    for (int s = 128; s > 0; s >>= 1) { if (t < s) red[t] += red[t + s]; __syncthreads(); }
    float var = red[0] * (1.0f / 256.0f);
    float o = d * rsqrtf(var + EPS_) * g[t] + b[t];
    out[(long)row * 256 + t] = o;
    outbf[(long)row * 256 + t] = __float2bfloat16(o);
}

// ctx_bf[3N, D] = bf16(concat(tokens[j], j != e))
__global__ void build_ctx(const float* __restrict__ tokens, bf16* __restrict__ ctx, int e) {
    long i = (long)blockIdx.x * 256 + threadIdx.x;
    if (i < (long)3 * N_ * D_) {
        int r = (int)(i >> 8);
        int d = (int)(i & 255);
        int c = r >> 11;
        int rn = r & 2047;
        int j = (c < e) ? c : c + 1;
        ctx[i] = __float2bfloat16(tokens[((long)j * N_ + rn) * D_ + d]);
    }
}

// f32 -> bf16 convert (n multiple of 4)
__global__ void cvt_bf16(const float* __restrict__ in, bf16* __restrict__ out, long n) {
    long i = ((long)blockIdx.x * 256 + threadIdx.x) * 4;
    if (i < n) {
        float4 v = *(const float4*)(in + i);
        out[i + 0] = __float2bfloat16(v.x);
        out[i + 1] = __float2bfloat16(v.y);
        out[i + 2] = __float2bfloat16(v.z);
        out[i + 3] = __float2bfloat16(v.w);
    }
}

__device__ inline float ldf(const float* p) { return *p; }
__device__ inline float ldf(const bf16* p)  { return __bfloat162float(*p); }

// out[c][r] = bf16(in[r][c]); R,C multiples of 64
template<typename T>
__global__ void transpose_bf16(const T* __restrict__ in, bf16* __restrict__ out,
                               int R, int C, int ldin, int ldout) {
    __shared__ float t[64][65];
    int tx = threadIdx.x & 63, ty = threadIdx.x >> 6;
    int r0 = blockIdx.y * 64, c0 = blockIdx.x * 64;
    #pragma unroll
    for (int i = 0; i < 16; ++i) {
        int r = ty + i * 4;
        t[r][tx] = ldf(&in[(long)(r0 + r) * ldin + (c0 + tx)]);
    }
    __syncthreads();
    #pragma unroll
    for (int i = 0; i < 16; ++i) {
        int c = ty + i * 4;
        out[(long)(c0 + c) * ldout + (r0 + tx)] = __float2bfloat16(t[tx][c]);
    }
}

__global__ void mem_update(const float* __restrict__ mem, const float* __restrict__ upd,
                           float* __restrict__ out) {
    long i = (long)blockIdx.x * 256 + threadIdx.x;
    if (i < (long)L_ * M_ * D_) out[i] = (1.0f - GAMMA_) * mem[i] + GAMMA_ * upd[i];
}

__global__ void pool_partial(const float* __restrict__ xf, float* __restrict__ pooled) {
    int e = blockIdx.x, chunk = blockIdx.y, t = threadIdx.x;
    float s = 0.f;
    int n0 = chunk * (N_ / 16);
    for (int n = n0; n < n0 + N_ / 16; ++n)
        s += xf[((long)e * N_ + n) * D_ + t];
    atomicAdd(&pooled[e * D_ + t], s * (1.0f / (float)N_));
}

__global__ void gate_kernel(const float* __restrict__ pooled, const float* __restrict__ gg,
                            float* __restrict__ out_gate, float* __restrict__ ws_gate) {
    __shared__ float red[256];
    __shared__ float logits[4];
    int t = threadIdx.x;
    for (int e = 0; e < 4; ++e) {
        red[t] = pooled[e * 256 + t] * gg[t];
        __syncthreads();
        for (int s = 128; s > 0; s >>= 1) { if (t < s) red[t] += red[t + s]; __syncthreads(); }
        if (t == 0) logits[e] = red[0];
        __syncthreads();
    }
    if (t == 0) {
        float m = fmaxf(fmaxf(logits[0], logits[1]), fmaxf(logits[2], logits[3]));
        float g[4]; float s = 0.f;
        for (int e = 0; e < 4; ++e) { g[e] = __expf(logits[e] - m); s += g[e]; }
        for (int e = 0; e < 4; ++e) {
            float w = g[e] / s;
            out_gate[e] = w;
            ws_gate[e] = w;
        }
    }
}

__global__ void fuse_kernel(const float* __restrict__ xf, const float* __restrict__ g4,
                            float* __restrict__ out) {
    long i = (long)blockIdx.x * 256 + threadIdx.x;
    const long ND = (long)N_ * D_;
    if (i < ND)
        out[i] = g4[0] * xf[i] + g4[1] * xf[ND + i] + g4[2] * xf[2 * ND + i] + g4[3] * xf[3 * ND + i];
}

// ---------------------------------------------------------------------------

static void gemm(hipStream_t s, const bf16* A, int lda, const bf16* Bt, int ldb,
                 float* C, int ldc, bf16* Cbf, int M, int N, int K, int Kc,
                 float alpha, const float* bias, const float* res, int ldres,
                 int flags, const bf16* zb) {
    dim3 g((N + 127) / 128, (M + 127) / 128, (K + Kc - 1) / Kc);
    gemm_bf16<<<g, dim3(256), 0, s>>>(A, lda, Bt, ldb, C, ldc, Cbf, M, N, K, Kc,
                                      alpha, bias, res, ldres, flags, zb);
}

static void transposeF(hipStream_t s, const float* in, bf16* out, int R, int C, int ldin, int ldout) {
    transpose_bf16<float><<<dim3(C / 64, R / 64), dim3(256), 0, s>>>(in, out, R, C, ldin, ldout);
}
static void transposeB(hipStream_t s, const bf16* in, bf16* out, int R, int C, int ldin, int ldout) {
    transpose_bf16<bf16><<<dim3(C / 64, R / 64), dim3(256), 0, s>>>(in, out, R, C, ldin, ldout);
}
static void convert(hipStream_t s, const float* in, bf16* out, long n) {
    cvt_bf16<<<dim3((unsigned)((n / 4 + 255) / 256)), dim3(256), 0, s>>>(in, out, n);
}

extern "C" void kernel_launch(void* const* d_in, const int* in_sizes, int n_in,
                              void* d_out, int out_size, void* d_ws, size_t ws_size,
                              hipStream_t stream) {
    const float* tokens    = (const float*)d_in[0];
    const float* memories  = (const float*)d_in[1];
    const float* in_proj_w = (const float*)d_in[2];
    const float* in_proj_b = (const float*)d_in[3];
    const float* out_w     = (const float*)d_in[4];
    const float* out_b     = (const float*)d_in[5];
    const float* lin1_w    = (const float*)d_in[6];
    const float* lin1_b    = (const float*)d_in[7];
    const float* lin2_w    = (const float*)d_in[8];
    const float* lin2_b    = (const float*)d_in[9];
    const float* ln1_w     = (const float*)d_in[10];
    const float* ln1_b     = (const float*)d_in[11];
    const float* ln2_w     = (const float*)d_in[12];
    const float* ln2_b     = (const float*)d_in[13];
    const float* agg_w     = (const float*)d_in[14];
    const float* agg_b     = (const float*)d_in[15];
    const float* gg        = (const float*)d_in[16];

    // ---- workspace layout ----
    char* p = (char*)d_ws;
    auto alloc = [&](size_t bytes) { char* r = p; p += (bytes + 255) & ~(size_t)255; return r; };

    float* S        = (float*)alloc((size_t)N_ * 6144 * 4);       // 50.3 MB (score buffer)
    bf16*  PT_bf    = (bf16*)S;                                   // alias: [4096,2048] bf16, used after S dead
    bf16*  P_bf     = (bf16*)alloc((size_t)N_ * 6144 * 2);        // 25.2 MB
    float* updsum   = (float*)alloc((size_t)L_ * M_ * D_ * 4);    // 12.6 MB
    float* xfinal   = (float*)alloc((size_t)E_ * N_ * D_ * 4);    // 8.4 MB
    float* retcat   = (float*)alloc((size_t)N_ * 3 * D_ * 4);     // 6.3 MB
    bf16*  retc_bf  = (bf16*)alloc((size_t)N_ * 3 * D_ * 2);
    bf16*  tok_bf   = (bf16*)alloc((size_t)E_ * N_ * D_ * 2);
    bf16*  ctx_bf   = (bf16*)alloc((size_t)3 * N_ * D_ * 2);
    bf16*  ctxT_bf  = (bf16*)alloc((size_t)3 * N_ * D_ * 2);
    bf16*  mem_bf   = (bf16*)alloc((size_t)L_ * M_ * D_ * 2);
    bf16*  memT_bf  = (bf16*)alloc((size_t)L_ * M_ * D_ * 2);
    bf16*  ipw_bf   = (bf16*)alloc((size_t)E_ * 3 * D_ * D_ * 2);
    bf16*  outw_bf  = (bf16*)alloc((size_t)E_ * D_ * D_ * 2);
    bf16*  l1w_bf   = (bf16*)alloc((size_t)E_ * F_ * D_ * 2);
    bf16*  l2w_bf   = (bf16*)alloc((size_t)E_ * D_ * F_ * 2);
    bf16*  aggw_bf  = (bf16*)alloc((size_t)D_ * 3 * D_ * 2);
    bf16*  qkv_bf   = (bf16*)alloc((size_t)N_ * 3 * D_ * 2);
    bf16*  vT_bf    = (bf16*)alloc((size_t)D_ * N_ * 2);
    float* x0       = (float*)alloc((size_t)N_ * D_ * 4);
    bf16*  x0_bf    = (bf16*)alloc((size_t)N_ * D_ * 2);
    float* x1       = (float*)alloc((size_t)N_ * D_ * 4);
    bf16*  x1_bf    = (bf16*)alloc((size_t)N_ * D_ * 2);
    float* ybuf     = (float*)alloc((size_t)N_ * D_ * 4);
    bf16*  x2_bf    = (bf16*)alloc((size_t)N_ * D_ * 2);
    bf16*  x2T_bf   = (bf16*)alloc((size_t)D_ * N_ * 2);
    bf16*  obuf_bf  = (bf16*)alloc((size_t)N_ * D_ * 2);
    bf16*  hid_bf   = (bf16*)alloc((size_t)N_ * F_ * 2);
    float* pooled   = (float*)alloc(1024 * 4);
    float* gatebuf  = (float*)alloc(64);
    bf16*  zerobuf  = (bf16*)alloc(64);

    float* out_fused = (float*)d_out;
    float* out_gate  = out_fused + (long)N_ * D_;
    float* out_mem   = out_gate + E_;

    const float scaleD = 1.0f / 16.0f;          // 1/sqrt(256)
    const float scaleH = 0.17677669529663687f;  // 1/sqrt(32)

    hipMemsetAsync(zerobuf, 0, 64, stream);
    hipMemsetAsync(pooled, 0, 1024 * 4, stream);
    hipMemsetAsync(updsum, 0, (size_t)L_ * M_ * D_ * 4, stream);

    // one-time conversions
    convert(stream, tokens, tok_bf, (long)E_ * N_ * D_);
    convert(stream, memories, mem_bf, (long)L_ * M_ * D_);
    convert(stream, in_proj_w, ipw_bf, (long)E_ * 3 * D_ * D_);
    convert(stream, out_w, outw_bf, (long)E_ * D_ * D_);
    convert(stream, lin1_w, l1w_bf, (long)E_ * F_ * D_);
    convert(stream, lin2_w, l2w_bf, (long)E_ * D_ * F_);
    convert(stream, agg_w, aggw_bf, (long)D_ * 3 * D_);
    for (int l = 0; l < L_; ++l)
        transposeF(stream, memories + (long)l * M_ * D_, memT_bf + (long)l * M_ * D_, M_, D_, D_, M_);

    for (int e = 0; e < E_; ++e) {
        const float* tok = tokens + (long)e * N_ * D_;
        const bf16*  tkb = tok_bf + (long)e * N_ * D_;
        float* x2 = xfinal + (long)e * N_ * D_;

        // ---- cross-expert attention ----
        build_ctx<<<dim3((3 * N_ * D_ + 255) / 256), dim3(256), 0, stream>>>(tokens, ctx_bf, e);
        transposeB(stream, ctx_bf, ctxT_bf, 3 * N_, D_, D_, 3 * N_);
        gemm(stream, tkb, D_, ctx_bf, D_, S, 3 * N_, nullptr,
             N_, 3 * N_, D_, D_, scaleD, nullptr, nullptr, 0, 0, zerobuf);
        softmax_rows<<<dim3(N_), dim3(256), 0, stream>>>(S, P_bf, 3 * N_);
        hipMemsetAsync(x0, 0, (size_t)N_ * D_ * 4, stream);
        gemm(stream, P_bf, 3 * N_, ctxT_bf, 3 * N_, x0, D_, nullptr,
             N_, D_, 3 * N_, 768, 1.0f, nullptr, tok, D_, GF_ATOMIC, zerobuf);
        convert(stream, x0, x0_bf, (long)N_ * D_);

        // ---- MHA ----
        gemm(stream, x0_bf, D_, ipw_bf + (long)e * 3 * D_ * D_, D_, nullptr, 3 * D_, qkv_bf,
             N_, 3 * D_, D_, D_, 1.0f, in_proj_b + (long)e * 3 * D_, nullptr, 0, 0, zerobuf);
        transposeB(stream, qkv_bf + 2 * D_, vT_bf, N_, D_, 3 * D_, N_);
        for (int h = 0; h < H_; ++h) {
            gemm(stream, qkv_bf + h * 32, 3 * D_, qkv_bf + D_ + h * 32, 3 * D_, S, N_, nullptr,
                 N_, N_, 32, 64, scaleH, nullptr, nullptr, 0, 0, zerobuf);
            softmax_rows<<<dim3(N_), dim3(256), 0, stream>>>(S, P_bf, N_);
            gemm(stream, P_bf, N_, vT_bf + (long)h * 32 * N_, N_, nullptr, D_, obuf_bf + h * 32,
                 N_, 32, N_, N_, 1.0f, nullptr, nullptr, 0, 0, zerobuf);
        }
        gemm(stream, obuf_bf, D_, outw_bf + (long)e * D_ * D_, D_, ybuf, D_, nullptr,
             N_, D_, D_, D_, 1.0f, out_b + (long)e * D_, x0, D_, 0, zerobuf);
        layernorm_rows<<<dim3(N_), dim3(256), 0, stream>>>(ybuf, ln1_w + (long)e * D_,
                                                           ln1_b + (long)e * D_, x1, x1_bf);

        // ---- FFN ----
        gemm(stream, x1_bf, D_, l1w_bf + (long)e * F_ * D_, D_, nullptr, F_, hid_bf,
             N_, F_, D_, D_, 1.0f, lin1_b + (long)e * F_, nullptr, 0, GF_RELU, zerobuf);
        hipMemsetAsync(ybuf, 0, (size_t)N_ * D_ * 4, stream);
        gemm(stream, hid_bf, F_, l2w_bf + (long)e * D_ * F_, F_, ybuf, D_, nullptr,
             N_, D_, F_, 256, 1.0f, lin2_b + (long)e * D_, x1, D_, GF_ATOMIC, zerobuf);
        layernorm_rows<<<dim3(N_), dim3(256), 0, stream>>>(ybuf, ln2_w + (long)e * D_,
                                                           ln2_b + (long)e * D_, x2, x2_bf);
        transposeF(stream, x2, x2T_bf, N_, D_, D_, N_);

        // ---- memory read/write ----
        hipMemsetAsync(retcat, 0, (size_t)N_ * 3 * D_ * 4, stream);
        for (int l = 0; l < L_; ++l) {
            gemm(stream, x2_bf, D_, mem_bf + (long)l * M_ * D_, D_, S, M_, nullptr,
                 N_, M_, D_, D_, scaleD, nullptr, nullptr, 0, 0, zerobuf);
            softmax_rows<<<dim3(N_), dim3(256), 0, stream>>>(S, P_bf, M_);
            transposeB(stream, P_bf, PT_bf, N_, M_, M_, N_);   // PT aliases S (S dead here)
            gemm(stream, P_bf, M_, memT_bf + (long)l * M_ * D_, M_, retcat + l * D_, 3 * D_, nullptr,
                 N_, D_, M_, 512, 1.0f, nullptr, nullptr, 0, GF_ATOMIC, zerobuf);
            gemm(stream, PT_bf, N_, x2T_bf, N_, updsum + (long)l * M_ * D_, D_, nullptr,
                 M_, D_, N_, 512, 1.0f, nullptr, nullptr, 0, GF_ATOMIC, zerobuf);
        }
        convert(stream, retcat, retc_bf, (long)N_ * 3 * D_);
        gemm(stream, retc_bf, 3 * D_, aggw_bf, 3 * D_, x2, D_, nullptr,
             N_, D_, 3 * D_, 3 * D_, 1.0f, agg_b, x2, D_, 0, zerobuf);
    }

    mem_update<<<dim3((L_ * M_ * D_ + 255) / 256), dim3(256), 0, stream>>>(memories, updsum, out_mem);
    pool_partial<<<dim3(E_, 16), dim3(256), 0, stream>>>(xfinal, pooled);
    gate_kernel<<<dim3(1), dim3(256), 0, stream>>>(pooled, gg, out_gate, gatebuf);
    fuse_kernel<<<dim3((N_ * D_ + 255) / 256), dim3(256), 0, stream>>>(xfinal, gatebuf, out_fused);
}

// Round 3
// 2098.029 us; speedup vs baseline: 16.0649x; 2.0493x over previous
//
#include <hip/hip_runtime.h>
#include <hip/hip_bf16.h>
#include <math.h>

#define E_ 4
#define N_ 2048
#define D_ 256
#define H_ 8
#define F_ 2048
#define M_ 4096
#define L_ 3
#define GAMMA_ 0.1f
#define EPS_ 1e-5f

#define GF_ATOMIC 1
#define GF_RELU   2

typedef __attribute__((ext_vector_type(8))) short  sh8;
typedef __attribute__((ext_vector_type(4))) float  fx4;
typedef __hip_bfloat16 bf16;

#define MFMA16 __builtin_amdgcn_mfma_f32_16x16x32_bf16

__device__ inline void gload_lds16(const void* g, void* l) {
    __builtin_amdgcn_global_load_lds((const __attribute__((address_space(1))) void*)g,
                                     (__attribute__((address_space(3))) void*)l, 16, 0, 0);
}

// ---------------------------------------------------------------------------
// bf16 MFMA GEMM, C[M,N] = alpha*A@Bt^T (+bias)(+res). A:[M,K] lda; Bt:[N,K] ldb.
// BN: 128 or 64 (BM always 128). Split-K over blockIdx.z (chunk Kc).
// Per-expert weights: expert = (blockIdx.y*128)>>11; Bt += e*wstride, bias += e*bstride.
// ---------------------------------------------------------------------------
template<int BN>
__global__ __launch_bounds__(256, 4)
void gemm_bf16(const bf16* __restrict__ A, int lda,
               const bf16* __restrict__ Bt, int ldb, long wstride,
               float* C, int ldc, bf16* Cbf,
               int M, int N, int K, int Kc,
               float alpha, const float* __restrict__ bias, long bstride,
               const float* res, int ldres, int flags,
               const bf16* __restrict__ zerobuf)
{
    constexpr int MI  = (BN == 128) ? 4 : 2;
    constexpr int BCH = BN * 8 / 256;          // B chunks per thread
    __shared__ char smem[16384 + BN * 128];
    char* sA = smem;
    char* sB = smem + 16384;
    const int tid  = threadIdx.x;
    const int lane = tid & 63;
    const int lo   = lane & 15, hi = lane >> 4;
    const int wid  = tid >> 6;
    const int rowbase = (BN == 128) ? (wid >> 1) * 64 : wid * 32;
    const int colbase = (BN == 128) ? (wid & 1) * 64 : 0;
    const int bm = blockIdx.y * 128, bn = blockIdx.x * BN;

    const int eid = (blockIdx.y * 128) >> 11;
    const bf16* Bte = Bt + (long)eid * wstride;
    const float* biase = bias ? (bias + (long)eid * bstride) : nullptr;

    const int kbeg = blockIdx.z * Kc;
    const int kend = min(K, kbeg + Kc);

    fx4 acc[MI][4] = {};

    for (int k0 = kbeg; k0 < kend; k0 += 64) {
        #pragma unroll
        for (int i = 0; i < 4; ++i) {                 // A tile [128][64]
            int id  = i * 256 + tid;
            int row = id >> 3;
            int c   = (id & 7) ^ (row & 7);
            int gk  = k0 + c * 8;
            const bf16* gp = (gk < kend) ? (A + (long)(bm + row) * lda + gk) : zerobuf;
            gload_lds16(gp, sA + id * 16);
        }
        #pragma unroll
        for (int i = 0; i < BCH; ++i) {               // B tile [BN][64]
            int id  = i * 256 + tid;
            int row = id >> 3;
            int c   = (id & 7) ^ (row & 7);
            int gk  = k0 + c * 8;
            const bf16* gp = (gk < kend && bn + row < N) ? (Bte + (long)(bn + row) * ldb + gk)
                                                         : zerobuf;
            gload_lds16(gp, sB + id * 16);
        }
        asm volatile("s_waitcnt vmcnt(0)" ::: "memory");
        __syncthreads();

        #pragma unroll
        for (int kk = 0; kk < 2; ++kk) {
            const int ko = kk * 32 + hi * 8;
            sh8 af[MI], bfr[4];
            #pragma unroll
            for (int i = 0; i < MI; ++i) {
                int row = rowbase + i * 16 + lo;
                int off = (row * 128 + ko * 2) ^ ((row & 7) << 4);
                af[i] = *(const sh8*)(sA + off);
            }
            #pragma unroll
            for (int j = 0; j < 4; ++j) {
                int row = colbase + j * 16 + lo;
                int off = (row * 128 + ko * 2) ^ ((row & 7) << 4);
                bfr[j] = *(const sh8*)(sB + off);
            }
            #pragma unroll
            for (int i = 0; i < MI; ++i)
                #pragma unroll
                for (int j = 0; j < 4; ++j)
                    acc[i][j] = MFMA16(af[i], bfr[j], acc[i][j], 0, 0, 0);
        }
        __syncthreads();
    }

    const bool z0 = (blockIdx.z == 0);
    #pragma unroll
    for (int j = 0; j < 4; ++j) {
        int col = bn + colbase + j * 16 + lo;
        if (col >= N) continue;
        #pragma unroll
        for (int i = 0; i < MI; ++i) {
            #pragma unroll
            for (int r = 0; r < 4; ++r) {
                int row = bm + rowbase + i * 16 + hi * 4 + r;
                float v = alpha * acc[i][j][r];
                if (z0) {
                    if (biase) v += biase[col];
                    if (res)   v += res[(long)row * ldres + col];
                }
                if (flags & GF_RELU) v = fmaxf(v, 0.f);
                long idx = (long)row * ldc + col;
                if (flags & GF_ATOMIC) atomicAdd(&C[idx], v);
                else {
                    if (C)   C[idx] = v;
                    if (Cbf) Cbf[idx] = __float2bfloat16(v);
                }
            }
        }
    }
}

// ---------------------------------------------------------------------------
// Flash MHA: grid (N/64, H, E), 256 thr (4 waves, 16 q-rows each). hd=32.
// qkv: [E][N,768] bf16 (q|k|v). vT: [E][256][N] bf16 (d-major). out: obuf [E*N, 256].
// ---------------------------------------------------------------------------
__global__ __launch_bounds__(256, 2)
void flash_mha(const bf16* __restrict__ qkv, const bf16* __restrict__ vT,
               bf16* __restrict__ obuf)
{
    const int e = blockIdx.z, h = blockIdx.y;
    const int n0 = blockIdx.x * 64;
    const int tid = threadIdx.x, lane = tid & 63, w = tid >> 6;
    const int lo = lane & 15, hi = lane >> 4;
    const float scaleH = 0.17677669529663687f;  // 1/sqrt(32)
    const bf16* qkv_e = qkv + (long)e * N_ * 768;
    const bf16* vT_eh = vT + ((long)e * D_ + h * 32) * N_;
    __shared__ bf16 Plds[4][16][64];

    sh8 qf = *(const sh8*)(qkv_e + (long)(n0 + w * 16 + lo) * 768 + h * 32 + hi * 8);

    float m[4], l[4];
    fx4 acc[2] = {};
    #pragma unroll
    for (int r = 0; r < 4; ++r) { m[r] = -INFINITY; l[r] = 0.f; }

    for (int kc = 0; kc < N_; kc += 64) {
        float sv[4][4], rmax[4], rsum[4];
        #pragma unroll
        for (int j = 0; j < 4; ++j) {
            sh8 kf = *(const sh8*)(qkv_e + (long)(kc + j * 16 + lo) * 768 + 256 + h * 32 + hi * 8);
            fx4 s = {};
            s = MFMA16(qf, kf, s, 0, 0, 0);
            #pragma unroll
            for (int r = 0; r < 4; ++r) sv[j][r] = s[r] * scaleH;
        }
        #pragma unroll
        for (int r = 0; r < 4; ++r) {
            rmax[r] = fmaxf(fmaxf(sv[0][r], sv[1][r]), fmaxf(sv[2][r], sv[3][r]));
        }
        #pragma unroll
        for (int d = 1; d < 16; d <<= 1)
            #pragma unroll
            for (int r = 0; r < 4; ++r) rmax[r] = fmaxf(rmax[r], __shfl_xor(rmax[r], d, 64));
        float sc[4];
        #pragma unroll
        for (int r = 0; r < 4; ++r) {
            float mn = fmaxf(m[r], rmax[r]);
            sc[r] = __expf(m[r] - mn);
            m[r] = mn;
            rsum[r] = 0.f;
        }
        #pragma unroll
        for (int j = 0; j < 4; ++j)
            #pragma unroll
            for (int r = 0; r < 4; ++r) {
                float p = __expf(sv[j][r] - m[r]);
                sv[j][r] = p; rsum[r] += p;
            }
        #pragma unroll
        for (int d = 1; d < 16; d <<= 1)
            #pragma unroll
            for (int r = 0; r < 4; ++r) rsum[r] += __shfl_xor(rsum[r], d, 64);
        #pragma unroll
        for (int r = 0; r < 4; ++r) l[r] = l[r] * sc[r] + rsum[r];
        #pragma unroll
        for (int j2 = 0; j2 < 2; ++j2)
            #pragma unroll
            for (int r = 0; r < 4; ++r) acc[j2][r] *= sc[r];
        // P -> LDS strip (per-wave, no cross-wave sharing)
        #pragma unroll
        for (int j = 0; j < 4; ++j)
            #pragma unroll
            for (int r = 0; r < 4; ++r)
                Plds[w][hi * 4 + r][j * 16 + lo] = __float2bfloat16(sv[j][r]);
        asm volatile("s_waitcnt lgkmcnt(0)" ::: "memory");
        #pragma unroll
        for (int ks = 0; ks < 2; ++ks) {
            sh8 pa = *(const sh8*)(&Plds[w][lo][ks * 32 + hi * 8]);
            #pragma unroll
            for (int j2 = 0; j2 < 2; ++j2) {
                sh8 vb = *(const sh8*)(vT_eh + (long)(j2 * 16 + lo) * N_ + kc + ks * 32 + hi * 8);
                acc[j2] = MFMA16(pa, vb, acc[j2], 0, 0, 0);
            }
        }
    }
    #pragma unroll
    for (int j2 = 0; j2 < 2; ++j2)
        #pragma unroll
        for (int r = 0; r < 4; ++r) {
            long row = (long)e * N_ + n0 + w * 16 + hi * 4 + r;
            obuf[row * D_ + h * 32 + j2 * 16 + lo] = __float2bfloat16(acc[j2][r] / l[r]);
        }
}

// ---------------------------------------------------------------------------
// Flash cross-attention: grid (N/64, 2 halves, E). ctx = other experts' tokens
// (6144 keys, split 3072/half). Writes unnormalized partial O + (m,l).
// ---------------------------------------------------------------------------
__global__ __launch_bounds__(256, 2)
void flash_cross(const bf16* __restrict__ tok, const bf16* __restrict__ tokT,
                 float* __restrict__ Opart, float2* __restrict__ ml)
{
    const int e = blockIdx.z, half = blockIdx.y;
    const int n0 = blockIdx.x * 64;
    const int tid = threadIdx.x, lane = tid & 63, w = tid >> 6;
    const int lo = lane & 15, hi = lane >> 4;
    const float scaleD = 1.0f / 16.0f;
    __shared__ bf16 Plds[4][16][64];

    sh8 qf[8];
    {
        const bf16* qr = tok + ((long)e * N_ + n0 + w * 16 + lo) * D_;
        #pragma unroll
        for (int ks = 0; ks < 8; ++ks) qf[ks] = *(const sh8*)(qr + ks * 32 + hi * 8);
    }
    float m[4], l[4];
    fx4 acc[16] = {};
    #pragma unroll
    for (int r = 0; r < 4; ++r) { m[r] = -INFINITY; l[r] = 0.f; }

    for (int kc = half * 3072; kc < half * 3072 + 3072; kc += 64) {
        const int seg = kc >> 11;
        const int src = (seg < e) ? seg : seg + 1;
        const int rowb = kc & 2047;
        float sv[4][4], rmax[4], rsum[4];
        #pragma unroll
        for (int j = 0; j < 4; ++j) {
            const bf16* kr = tok + ((long)src * N_ + rowb + j * 16 + lo) * D_;
            fx4 s = {};
            #pragma unroll
            for (int ks = 0; ks < 8; ++ks) {
                sh8 kf = *(const sh8*)(kr + ks * 32 + hi * 8);
                s = MFMA16(qf[ks], kf, s, 0, 0, 0);
            }
            #pragma unroll
            for (int r = 0; r < 4; ++r) sv[j][r] = s[r] * scaleD;
        }
        #pragma unroll
        for (int r = 0; r < 4; ++r)
            rmax[r] = fmaxf(fmaxf(sv[0][r], sv[1][r]), fmaxf(sv[2][r], sv[3][r]));
        #pragma unroll
        for (int d = 1; d < 16; d <<= 1)
            #pragma unroll
            for (int r = 0; r < 4; ++r) rmax[r] = fmaxf(rmax[r], __shfl_xor(rmax[r], d, 64));
        float sc[4];
        #pragma unroll
        for (int r = 0; r < 4; ++r) {
            float mn = fmaxf(m[r], rmax[r]);
            sc[r] = __expf(m[r] - mn);
            m[r] = mn; rsum[r] = 0.f;
        }
        #pragma unroll
        for (int j = 0; j < 4; ++j)
            #pragma unroll
            for (int r = 0; r < 4; ++r) {
                float p = __expf(sv[j][r] - m[r]);
                sv[j][r] = p; rsum[r] += p;
            }
        #pragma unroll
        for (int d = 1; d < 16; d <<= 1)
            #pragma unroll
            for (int r = 0; r < 4; ++r) rsum[r] += __shfl_xor(rsum[r], d, 64);
        #pragma unroll
        for (int r = 0; r < 4; ++r) l[r] = l[r] * sc[r] + rsum[r];
        #pragma unroll
        for (int j2 = 0; j2 < 16; ++j2)
            #pragma unroll
            for (int r = 0; r < 4; ++r) acc[j2][r] *= sc[r];
        #pragma unroll
        for (int j = 0; j < 4; ++j)
            #pragma unroll
            for (int r = 0; r < 4; ++r)
                Plds[w][hi * 4 + r][j * 16 + lo] = __float2bfloat16(sv[j][r]);
        asm volatile("s_waitcnt lgkmcnt(0)" ::: "memory");
        #pragma unroll
        for (int ks = 0; ks < 2; ++ks) {
            sh8 pa = *(const sh8*)(&Plds[w][lo][ks * 32 + hi * 8]);
            #pragma unroll
            for (int j2 = 0; j2 < 16; ++j2) {
                sh8 vb = *(const sh8*)(tokT + ((long)src * D_ + j2 * 16 + lo) * N_
                                       + rowb + ks * 32 + hi * 8);
                acc[j2] = MFMA16(pa, vb, acc[j2], 0, 0, 0);
            }
        }
    }
    const long base = (long)half * E_ * N_ + (long)e * N_ + n0 + w * 16;
    #pragma unroll
    for (int j2 = 0; j2 < 16; ++j2)
        #pragma unroll
        for (int r = 0; r < 4; ++r)
            Opart[(base + hi * 4 + r) * D_ + j2 * 16 + lo] = acc[j2][r];
    if (lo == 0) {
        #pragma unroll
        for (int r = 0; r < 4; ++r) {
            float2 t; t.x = m[r]; t.y = l[r];
            ml[base + hi * 4 + r] = t;
        }
    }
}

// Merge the two ctx-halves, add token residual: x0 = tok + O. grid (E*N), 256 thr.
__global__ void cross_merge(const float* __restrict__ Opart, const float2* __restrict__ ml,
                            const float* __restrict__ tokens,
                            float* __restrict__ x0f, bf16* __restrict__ x0bf)
{
    long row = blockIdx.x; int d = threadIdx.x;
    float2 a = ml[row], b = ml[(long)E_ * N_ + row];
    float mx = fmaxf(a.x, b.x);
    float e0 = __expf(a.x - mx), e1 = __expf(b.x - mx);
    float denom = a.y * e0 + b.y * e1;
    float o = (Opart[row * D_ + d] * e0 + Opart[((long)E_ * N_ + row) * D_ + d] * e1) / denom;
    float v = tokens[row * D_ + d] + o;
    x0f[row * D_ + d] = v;
    x0bf[row * D_ + d] = __float2bfloat16(v);
}

// Row softmax: f32 in -> bf16 out, cols <= 4096. One block per row.
__global__ void softmax_rows(const float* __restrict__ S, bf16* __restrict__ P, int cols) {
    __shared__ float buf[4096];
    __shared__ float red[256];
    int row = blockIdx.x, t = threadIdx.x;
    const float* r = S + (long)row * cols;
    float lmax = -INFINITY;
    for (int c = t; c < cols; c += 256) { float v = r[c]; buf[c] = v; lmax = fmaxf(lmax, v); }
    red[t] = lmax; __syncthreads();
    for (int s = 128; s > 0; s >>= 1) { if (t < s) red[t] = fmaxf(red[t], red[t + s]); __syncthreads(); }
    float mm = red[0]; __syncthreads();
    float lsum = 0.f;
    for (int c = t; c < cols; c += 256) { float e = __expf(buf[c] - mm); buf[c] = e; lsum += e; }
    red[t] = lsum; __syncthreads();
    for (int s = 128; s > 0; s >>= 1) { if (t < s) red[t] += red[t + s]; __syncthreads(); }
    float inv = 1.0f / red[0];
    bf16* o = P + (long)row * cols;
    for (int c = t; c < cols; c += 256) o[c] = __float2bfloat16(buf[c] * inv);
}

// LayerNorm over D=256, per-expert weights (expert = row>>11). f32 + bf16 out.
__global__ void layernorm_rows(const float* __restrict__ X, const float* __restrict__ g,
                               const float* __restrict__ b, float* __restrict__ out,
                               bf16* __restrict__ outbf)
{
    __shared__ float red[256];
    int row = blockIdx.x, t = threadIdx.x;
    int e = row >> 11;
    float v = X[(long)row * 256 + t];
    red[t] = v; __syncthreads();
    for (int s = 128; s > 0; s >>= 1) { if (t < s) red[t] += red[t + s]; __syncthreads(); }
    float mu = red[0] * (1.0f / 256.0f); __syncthreads();
    float d = v - mu;
    red[t] = d * d; __syncthreads();
    for (int s = 128; s > 0; s >>= 1) { if (t < s) red[t] += red[t + s]; __syncthreads(); }
    float var = red[0] * (1.0f / 256.0f);
    float o = d * rsqrtf(var + EPS_) * g[e * 256 + t] + b[e * 256 + t];
    out[(long)row * 256 + t] = o;
    outbf[(long)row * 256 + t] = __float2bfloat16(o);
}

__global__ void cvt_bf16(const float* __restrict__ in, bf16* __restrict__ out, long n) {
    long i = ((long)blockIdx.x * 256 + threadIdx.x) * 4;
    if (i < n) {
        float4 v = *(const float4*)(in + i);
        out[i + 0] = __float2bfloat16(v.x);
        out[i + 1] = __float2bfloat16(v.y);
        out[i + 2] = __float2bfloat16(v.z);
        out[i + 3] = __float2bfloat16(v.w);
    }
}

__device__ inline float ldf(const float* p) { return *p; }
__device__ inline float ldf(const bf16* p)  { return __bfloat162float(*p); }

template<typename T>
__global__ void transpose_bf16(const T* __restrict__ in, bf16* __restrict__ out,
                               int R, int C, int ldin, int ldout) {
    __shared__ float t[64][65];
    int tx = threadIdx.x & 63, ty = threadIdx.x >> 6;
    int r0 = blockIdx.y * 64, c0 = blockIdx.x * 64;
    #pragma unroll
    for (int i = 0; i < 16; ++i) {
        int r = ty + i * 4;
        t[r][tx] = ldf(&in[(long)(r0 + r) * ldin + (c0 + tx)]);
    }
    __syncthreads();
    #pragma unroll
    for (int i = 0; i < 16; ++i) {
        int c = ty + i * 4;
        out[(long)(c0 + c) * ldout + (r0 + tx)] = __float2bfloat16(t[tx][c]);
    }
}

__global__ void mem_update(const float* __restrict__ mem, const float* __restrict__ upd,
                           float* __restrict__ out) {
    long i = (long)blockIdx.x * 256 + threadIdx.x;
    if (i < (long)L_ * M_ * D_) out[i] = (1.0f - GAMMA_) * mem[i] + GAMMA_ * upd[i];
}

__global__ void pool_partial(const float* __restrict__ xf, float* __restrict__ pooled) {
    int e = blockIdx.x, chunk = blockIdx.y, t = threadIdx.x;
    float s = 0.f;
    int n0 = chunk * (N_ / 16);
    for (int n = n0; n < n0 + N_ / 16; ++n)
        s += xf[((long)e * N_ + n) * D_ + t];
    atomicAdd(&pooled[e * D_ + t], s * (1.0f / (float)N_));
}

__global__ void gate_kernel(const float* __restrict__ pooled, const float* __restrict__ gg,
                            float* __restrict__ out_gate, float* __restrict__ ws_gate) {
    __shared__ float red[256];
    __shared__ float logits[4];
    int t = threadIdx.x;
    for (int e = 0; e < 4; ++e) {
        red[t] = pooled[e * 256 + t] * gg[t];
        __syncthreads();
        for (int s = 128; s > 0; s >>= 1) { if (t < s) red[t] += red[t + s]; __syncthreads(); }
        if (t == 0) logits[e] = red[0];
        __syncthreads();
    }
    if (t == 0) {
        float mm = fmaxf(fmaxf(logits[0], logits[1]), fmaxf(logits[2], logits[3]));
        float g[4]; float s = 0.f;
        for (int e = 0; e < 4; ++e) { g[e] = __expf(logits[e] - mm); s += g[e]; }
        for (int e = 0; e < 4; ++e) {
            float w = g[e] / s;
            out_gate[e] = w;
            ws_gate[e] = w;
        }
    }
}

__global__ void fuse_kernel(const float* __restrict__ xf, const float* __restrict__ g4,
                            float* __restrict__ out) {
    long i = (long)blockIdx.x * 256 + threadIdx.x;
    const long ND = (long)N_ * D_;
    if (i < ND)
        out[i] = g4[0] * xf[i] + g4[1] * xf[ND + i] + g4[2] * xf[2 * ND + i] + g4[3] * xf[3 * ND + i];
}

// ---------------------------------------------------------------------------

static void gemm(hipStream_t s, int BN, const bf16* A, int lda, const bf16* Bt, int ldb,
                 long wstride, float* C, int ldc, bf16* Cbf, int M, int N, int K, int Kc,
                 float alpha, const float* bias, long bstride, const float* res, int ldres,
                 int flags, const bf16* zb) {
    dim3 g((N + BN - 1) / BN, (M + 127) / 128, (K + Kc - 1) / Kc);
    if (BN == 128)
        gemm_bf16<128><<<g, dim3(256), 0, s>>>(A, lda, Bt, ldb, wstride, C, ldc, Cbf, M, N, K, Kc,
                                               alpha, bias, bstride, res, ldres, flags, zb);
    else
        gemm_bf16<64><<<g, dim3(256), 0, s>>>(A, lda, Bt, ldb, wstride, C, ldc, Cbf, M, N, K, Kc,
                                              alpha, bias, bstride, res, ldres, flags, zb);
}

static void transposeF(hipStream_t s, const float* in, bf16* out, int R, int C, int ldin, int ldout) {
    transpose_bf16<float><<<dim3(C / 64, R / 64), dim3(256), 0, s>>>(in, out, R, C, ldin, ldout);
}
static void transposeB(hipStream_t s, const bf16* in, bf16* out, int R, int C, int ldin, int ldout) {
    transpose_bf16<bf16><<<dim3(C / 64, R / 64), dim3(256), 0, s>>>(in, out, R, C, ldin, ldout);
}
static void convert(hipStream_t s, const float* in, bf16* out, long n) {
    cvt_bf16<<<dim3((unsigned)((n / 4 + 255) / 256)), dim3(256), 0, s>>>(in, out, n);
}

extern "C" void kernel_launch(void* const* d_in, const int* in_sizes, int n_in,
                              void* d_out, int out_size, void* d_ws, size_t ws_size,
                              hipStream_t stream) {
    const float* tokens    = (const float*)d_in[0];
    const float* memories  = (const float*)d_in[1];
    const float* in_proj_w = (const float*)d_in[2];
    const float* in_proj_b = (const float*)d_in[3];
    const float* out_w     = (const float*)d_in[4];
    const float* out_b     = (const float*)d_in[5];
    const float* lin1_w    = (const float*)d_in[6];
    const float* lin1_b    = (const float*)d_in[7];
    const float* lin2_w    = (const float*)d_in[8];
    const float* lin2_b    = (const float*)d_in[9];
    const float* ln1_w     = (const float*)d_in[10];
    const float* ln1_b     = (const float*)d_in[11];
    const float* ln2_w     = (const float*)d_in[12];
    const float* ln2_b     = (const float*)d_in[13];
    const float* agg_w     = (const float*)d_in[14];
    const float* agg_b     = (const float*)d_in[15];
    const float* gg        = (const float*)d_in[16];

    char* p = (char*)d_ws;
    auto alloc = [&](size_t bytes) { char* r = p; p += (bytes + 255) & ~(size_t)255; return r; };

    // region0: 32MB, time-shared: Opart(cross, 16MB) -> hid_all(FFN, 32MB) -> S f32 / PT (mem)
    char*  region0 = alloc((size_t)32 * 1024 * 1024);
    float* Opart   = (float*)region0;                  // [2][8192][256] f32
    bf16*  hid_all = (bf16*)region0;                   // [8192][2048] bf16
    float* S       = (float*)region0;                  // [2048][4096] f32
    bf16*  PT_bf   = (bf16*)region0;                   // [4096][2048] bf16 (S dead)

    bf16*  P_bf    = (bf16*)alloc((size_t)N_ * M_ * 2);            // 16MB
    float* updsum  = (float*)alloc((size_t)L_ * M_ * D_ * 4);      // 12.6MB
    float* xfinal  = (float*)alloc((size_t)E_ * N_ * D_ * 4);      // 8MB
    bf16*  x2_bf   = (bf16*)alloc((size_t)E_ * N_ * D_ * 2);       // 4MB
    bf16*  x2T_bf  = (bf16*)alloc((size_t)E_ * D_ * N_ * 2);       // 4MB
    float* x0f     = (float*)alloc((size_t)E_ * N_ * D_ * 4);      // 8MB (aliased as x1 later)
    bf16*  x0bf    = (bf16*)alloc((size_t)E_ * N_ * D_ * 2);       // 4MB (aliased as x1bf later)
    float* ybuf    = (float*)alloc((size_t)E_ * N_ * D_ * 4);      // 8MB
    bf16*  obuf_bf = (bf16*)alloc((size_t)E_ * N_ * D_ * 2);       // 4MB
    bf16*  qkv_bf  = (bf16*)alloc((size_t)E_ * N_ * 3 * D_ * 2);   // 12MB
    bf16*  vT_bf   = (bf16*)alloc((size_t)E_ * D_ * N_ * 2);       // 4MB
    bf16*  tok_bf  = (bf16*)alloc((size_t)E_ * N_ * D_ * 2);       // 4MB
    bf16*  tokT_bf = (bf16*)alloc((size_t)E_ * D_ * N_ * 2);       // 4MB
    bf16*  mem_bf  = (bf16*)alloc((size_t)L_ * M_ * D_ * 2);       // 6MB
    bf16*  maggT   = (bf16*)alloc((size_t)L_ * D_ * M_ * 2);       // 6MB
    float2* mlbuf  = (float2*)alloc((size_t)2 * E_ * N_ * sizeof(float2));
    bf16*  ipw_bf  = (bf16*)alloc((size_t)E_ * 3 * D_ * D_ * 2);
    bf16*  outw_bf = (bf16*)alloc((size_t)E_ * D_ * D_ * 2);
    bf16*  l1w_bf  = (bf16*)alloc((size_t)E_ * F_ * D_ * 2);
    bf16*  l2w_bf  = (bf16*)alloc((size_t)E_ * D_ * F_ * 2);
    bf16*  aggw_bf = (bf16*)alloc((size_t)D_ * 3 * D_ * 2);
    float* pooled  = (float*)alloc(1024 * 4);
    float* gatebuf = (float*)alloc(64);
    bf16*  zerobuf = (bf16*)alloc(64);

    float* x1f  = x0f;    // x0 dead after out-proj (runs before LN1)
    bf16*  x1bf = x0bf;

    float* out_fused = (float*)d_out;
    float* out_gate  = out_fused + (long)N_ * D_;
    float* out_mem   = out_gate + E_;

    const float scaleD = 1.0f / 16.0f;

    hipMemsetAsync(zerobuf, 0, 64, stream);
    hipMemsetAsync(pooled, 0, 1024 * 4, stream);
    hipMemsetAsync(updsum, 0, (size_t)L_ * M_ * D_ * 4, stream);

    // one-time conversions / transposes
    convert(stream, tokens, tok_bf, (long)E_ * N_ * D_);
    convert(stream, memories, mem_bf, (long)L_ * M_ * D_);
    convert(stream, in_proj_w, ipw_bf, (long)E_ * 3 * D_ * D_);
    convert(stream, out_w, outw_bf, (long)E_ * D_ * D_);
    convert(stream, lin1_w, l1w_bf, (long)E_ * F_ * D_);
    convert(stream, lin2_w, l2w_bf, (long)E_ * D_ * F_);
    convert(stream, agg_w, aggw_bf, (long)D_ * 3 * D_);
    for (int e = 0; e < E_; ++e)
        transposeF(stream, tokens + (long)e * N_ * D_, tokT_bf + (long)e * D_ * N_, N_, D_, D_, N_);
    // maggT_l = agg_w_l @ mem_l^T : [256, 4096]
    for (int l = 0; l < L_; ++l)
        gemm(stream, 128, aggw_bf + l * D_, 3 * D_, mem_bf + (long)l * M_ * D_, D_, 0,
             nullptr, M_, maggT + (long)l * D_ * M_, D_, M_, D_, D_,
             1.0f, nullptr, 0, nullptr, 0, 0, zerobuf);

    // ---- cross-expert attention (flash, all experts) ----
    flash_cross<<<dim3(N_ / 64, 2, E_), dim3(256), 0, stream>>>(tok_bf, tokT_bf, Opart, mlbuf);
    cross_merge<<<dim3(E_ * N_), dim3(256), 0, stream>>>(Opart, mlbuf, tokens, x0f, x0bf);

    // ---- MHA (batched) ----
    gemm(stream, 128, x0bf, D_, ipw_bf, D_, (long)3 * D_ * D_,
         nullptr, 3 * D_, qkv_bf, E_ * N_, 3 * D_, D_, D_,
         1.0f, in_proj_b, 3 * D_, nullptr, 0, 0, zerobuf);
    for (int e = 0; e < E_; ++e)
        transposeB(stream, qkv_bf + (long)e * N_ * 3 * D_ + 2 * D_, vT_bf + (long)e * D_ * N_,
                   N_, D_, 3 * D_, N_);
    flash_mha<<<dim3(N_ / 64, H_, E_), dim3(256), 0, stream>>>(qkv_bf, vT_bf, obuf_bf);
    gemm(stream, 64, obuf_bf, D_, outw_bf, D_, (long)D_ * D_,
         ybuf, D_, nullptr, E_ * N_, D_, D_, D_,
         1.0f, out_b, D_, x0f, D_, 0, zerobuf);
    layernorm_rows<<<dim3(E_ * N_), dim3(256), 0, stream>>>(ybuf, ln1_w, ln1_b, x1f, x1bf);

    // ---- FFN (batched) ----
    gemm(stream, 128, x1bf, D_, l1w_bf, D_, (long)F_ * D_,
         nullptr, F_, hid_all, E_ * N_, F_, D_, D_,
         1.0f, lin1_b, F_, nullptr, 0, GF_RELU, zerobuf);
    hipMemsetAsync(ybuf, 0, (size_t)E_ * N_ * D_ * 4, stream);
    gemm(stream, 64, hid_all, F_, l2w_bf, F_, (long)D_ * F_,
         ybuf, D_, nullptr, E_ * N_, D_, F_, 512,
         1.0f, lin2_b, D_, x1f, D_, GF_ATOMIC, zerobuf);
    layernorm_rows<<<dim3(E_ * N_), dim3(256), 0, stream>>>(ybuf, ln2_w, ln2_b, xfinal, x2_bf);
    for (int e = 0; e < E_; ++e)
        transposeF(stream, xfinal + (long)e * N_ * D_, x2T_bf + (long)e * D_ * N_, N_, D_, D_, N_);

    // ---- memory read/write (per expert, per layer) ----
    for (int e = 0; e < E_; ++e) {
        const bf16* x2b = x2_bf + (long)e * N_ * D_;
        for (int l = 0; l < L_; ++l) {
            // S = x2 @ mem_l^T * scale  [2048, 4096]
            gemm(stream, 128, x2b, D_, mem_bf + (long)l * M_ * D_, D_, 0,
                 S, M_, nullptr, N_, M_, D_, D_,
                 scaleD, nullptr, 0, nullptr, 0, 0, zerobuf);
            softmax_rows<<<dim3(N_), dim3(256), 0, stream>>>(S, P_bf, M_);
            transposeB(stream, P_bf, PT_bf, N_, M_, M_, N_);   // PT aliases S (dead)
            // xfinal_e += P @ maggT_l^T (+agg_b once at l==0)
            gemm(stream, 64, P_bf, M_, maggT + (long)l * D_ * M_, M_, 0,
                 xfinal + (long)e * N_ * D_, D_, nullptr, N_, D_, M_, 512,
                 1.0f, (l == 0) ? agg_b : nullptr, 0, nullptr, 0, GF_ATOMIC, zerobuf);
            // updsum_l += P^T @ x2
            gemm(stream, 64, PT_bf, N_, x2T_bf + (long)e * D_ * N_, N_, 0,
                 updsum + (long)l * M_ * D_, D_, nullptr, M_, D_, N_, 512,
                 1.0f, nullptr, 0, nullptr, 0, GF_ATOMIC, zerobuf);
        }
    }

    mem_update<<<dim3((L_ * M_ * D_ + 255) / 256), dim3(256), 0, stream>>>(memories, updsum, out_mem);
    pool_partial<<<dim3(E_, 16), dim3(256), 0, stream>>>(xfinal, pooled);
    gate_kernel<<<dim3(1), dim3(256), 0, stream>>>(pooled, gg, out_gate, gatebuf);
    fuse_kernel<<<dim3((N_ * D_ + 255) / 256), dim3(256), 0, stream>>>(xfinal, gatebuf, out_fused);
}

// Round 4
// 1569.636 us; speedup vs baseline: 21.4730x; 1.3366x over previous
//
#include <hip/hip_runtime.h>
#include <hip/hip_bf16.h>
#include <math.h>

#define E_ 4
#define N_ 2048
#define D_ 256
#define H_ 8
#define F_ 2048
#define M_ 4096
#define L_ 3
#define GAMMA_ 0.1f
#define EPS_ 1e-5f
#define CCH 8   // cross-attention key chunks

#define GF_ATOMIC 1
#define GF_RELU   2

typedef __attribute__((ext_vector_type(8))) short  sh8;
typedef __attribute__((ext_vector_type(4))) float  fx4;
typedef __hip_bfloat16 bf16;

#define MFMA16 __builtin_amdgcn_mfma_f32_16x16x32_bf16

__device__ inline void gload_lds16(const void* g, void* l) {
    __builtin_amdgcn_global_load_lds((const __attribute__((address_space(1))) void*)g,
                                     (__attribute__((address_space(3))) void*)l, 16, 0, 0);
}

// Stage a [64][256] bf16 tile (row stride 512B) into LDS, XOR-swizzled source.
__device__ inline void stage_k64(const bf16* __restrict__ gbase, bf16* lds, int tid) {
    #pragma unroll
    for (int i = 0; i < 8; ++i) {
        int q = i * 256 + tid;
        int row = q >> 5, cst = q & 31;
        int cl = cst ^ (row & 7);
        gload_lds16((const char*)gbase + row * 512 + cl * 16, (char*)lds + q * 16);
    }
}
// Read the staged tile: row in [0,64), k-slice = ks*32 + hi*8 elements.
__device__ inline sh8 ldsK(const bf16* lds, int row, int ks, int hi) {
    return *(const sh8*)((const char*)lds + row * 512 + (((ks * 4 + hi) ^ (row & 7)) << 4));
}

// ---------------------------------------------------------------------------
// bf16 MFMA GEMM (unchanged from round 3)
// ---------------------------------------------------------------------------
template<int BN>
__global__ __launch_bounds__(256, 4)
void gemm_bf16(const bf16* __restrict__ A, int lda,
               const bf16* __restrict__ Bt, int ldb, long wstride,
               float* C, int ldc, bf16* Cbf,
               int M, int N, int K, int Kc,
               float alpha, const float* __restrict__ bias, long bstride,
               const float* res, int ldres, int flags,
               const bf16* __restrict__ zerobuf)
{
    constexpr int MI  = (BN == 128) ? 4 : 2;
    constexpr int BCH = BN * 8 / 256;
    __shared__ char smem[16384 + BN * 128];
    char* sA = smem;
    char* sB = smem + 16384;
    const int tid  = threadIdx.x;
    const int lane = tid & 63;
    const int lo   = lane & 15, hi = lane >> 4;
    const int wid  = tid >> 6;
    const int rowbase = (BN == 128) ? (wid >> 1) * 64 : wid * 32;
    const int colbase = (BN == 128) ? (wid & 1) * 64 : 0;
    const int bm = blockIdx.y * 128, bn = blockIdx.x * BN;

    const int eid = (blockIdx.y * 128) >> 11;
    const bf16* Bte = Bt + (long)eid * wstride;
    const float* biase = bias ? (bias + (long)eid * bstride) : nullptr;

    const int kbeg = blockIdx.z * Kc;
    const int kend = min(K, kbeg + Kc);

    fx4 acc[MI][4] = {};

    for (int k0 = kbeg; k0 < kend; k0 += 64) {
        #pragma unroll
        for (int i = 0; i < 4; ++i) {
            int id  = i * 256 + tid;
            int row = id >> 3;
            int c   = (id & 7) ^ (row & 7);
            int gk  = k0 + c * 8;
            const bf16* gp = (gk < kend) ? (A + (long)(bm + row) * lda + gk) : zerobuf;
            gload_lds16(gp, sA + id * 16);
        }
        #pragma unroll
        for (int i = 0; i < BCH; ++i) {
            int id  = i * 256 + tid;
            int row = id >> 3;
            int c   = (id & 7) ^ (row & 7);
            int gk  = k0 + c * 8;
            const bf16* gp = (gk < kend && bn + row < N) ? (Bte + (long)(bn + row) * ldb + gk)
                                                         : zerobuf;
            gload_lds16(gp, sB + id * 16);
        }
        asm volatile("s_waitcnt vmcnt(0)" ::: "memory");
        __syncthreads();

        #pragma unroll
        for (int kk = 0; kk < 2; ++kk) {
            const int ko = kk * 32 + hi * 8;
            sh8 af[MI], bfr[4];
            #pragma unroll
            for (int i = 0; i < MI; ++i) {
                int row = rowbase + i * 16 + lo;
                int off = (row * 128 + ko * 2) ^ ((row & 7) << 4);
                af[i] = *(const sh8*)(sA + off);
            }
            #pragma unroll
            for (int j = 0; j < 4; ++j) {
                int row = colbase + j * 16 + lo;
                int off = (row * 128 + ko * 2) ^ ((row & 7) << 4);
                bfr[j] = *(const sh8*)(sB + off);
            }
            #pragma unroll
            for (int i = 0; i < MI; ++i)
                #pragma unroll
                for (int j = 0; j < 4; ++j)
                    acc[i][j] = MFMA16(af[i], bfr[j], acc[i][j], 0, 0, 0);
        }
        __syncthreads();
    }

    const bool z0 = (blockIdx.z == 0);
    #pragma unroll
    for (int j = 0; j < 4; ++j) {
        int col = bn + colbase + j * 16 + lo;
        if (col >= N) continue;
        #pragma unroll
        for (int i = 0; i < MI; ++i) {
            #pragma unroll
            for (int r = 0; r < 4; ++r) {
                int row = bm + rowbase + i * 16 + hi * 4 + r;
                float v = alpha * acc[i][j][r];
                if (z0) {
                    if (biase) v += biase[col];
                    if (res)   v += res[(long)row * ldres + col];
                }
                if (flags & GF_RELU) v = fmaxf(v, 0.f);
                long idx = (long)row * ldc + col;
                if (flags & GF_ATOMIC) atomicAdd(&C[idx], v);
                else {
                    if (C)   C[idx] = v;
                    if (Cbf) Cbf[idx] = __float2bfloat16(v);
                }
            }
        }
    }
}

// ---------------------------------------------------------------------------
// Flash MHA (unchanged from round 3)
// ---------------------------------------------------------------------------
__global__ __launch_bounds__(256, 2)
void flash_mha(const bf16* __restrict__ qkv, const bf16* __restrict__ vT,
               bf16* __restrict__ obuf)
{
    const int e = blockIdx.z, h = blockIdx.y;
    const int n0 = blockIdx.x * 64;
    const int tid = threadIdx.x, lane = tid & 63, w = tid >> 6;
    const int lo = lane & 15, hi = lane >> 4;
    const float scaleH = 0.17677669529663687f;
    const bf16* qkv_e = qkv + (long)e * N_ * 768;
    const bf16* vT_eh = vT + ((long)e * D_ + h * 32) * N_;
    __shared__ bf16 Plds[4][16][64];

    sh8 qf = *(const sh8*)(qkv_e + (long)(n0 + w * 16 + lo) * 768 + h * 32 + hi * 8);

    float m[4], l[4];
    fx4 acc[2] = {};
    #pragma unroll
    for (int r = 0; r < 4; ++r) { m[r] = -INFINITY; l[r] = 0.f; }

    for (int kc = 0; kc < N_; kc += 64) {
        float sv[4][4], rmax[4], rsum[4];
        #pragma unroll
        for (int j = 0; j < 4; ++j) {
            sh8 kf = *(const sh8*)(qkv_e + (long)(kc + j * 16 + lo) * 768 + 256 + h * 32 + hi * 8);
            fx4 s = {};
            s = MFMA16(qf, kf, s, 0, 0, 0);
            #pragma unroll
            for (int r = 0; r < 4; ++r) sv[j][r] = s[r] * scaleH;
        }
        #pragma unroll
        for (int r = 0; r < 4; ++r)
            rmax[r] = fmaxf(fmaxf(sv[0][r], sv[1][r]), fmaxf(sv[2][r], sv[3][r]));
        #pragma unroll
        for (int d = 1; d < 16; d <<= 1)
            #pragma unroll
            for (int r = 0; r < 4; ++r) rmax[r] = fmaxf(rmax[r], __shfl_xor(rmax[r], d, 64));
        float sc[4];
        #pragma unroll
        for (int r = 0; r < 4; ++r) {
            float mn = fmaxf(m[r], rmax[r]);
            sc[r] = __expf(m[r] - mn);
            m[r] = mn; rsum[r] = 0.f;
        }
        #pragma unroll
        for (int j = 0; j < 4; ++j)
            #pragma unroll
            for (int r = 0; r < 4; ++r) {
                float p = __expf(sv[j][r] - m[r]);
                sv[j][r] = p; rsum[r] += p;
            }
        #pragma unroll
        for (int d = 1; d < 16; d <<= 1)
            #pragma unroll
            for (int r = 0; r < 4; ++r) rsum[r] += __shfl_xor(rsum[r], d, 64);
        #pragma unroll
        for (int r = 0; r < 4; ++r) l[r] = l[r] * sc[r] + rsum[r];
        #pragma unroll
        for (int j2 = 0; j2 < 2; ++j2)
            #pragma unroll
            for (int r = 0; r < 4; ++r) acc[j2][r] *= sc[r];
        #pragma unroll
        for (int j = 0; j < 4; ++j)
            #pragma unroll
            for (int r = 0; r < 4; ++r)
                Plds[w][hi * 4 + r][j * 16 + lo] = __float2bfloat16(sv[j][r]);
        asm volatile("s_waitcnt lgkmcnt(0)" ::: "memory");
        __builtin_amdgcn_sched_barrier(0);
        #pragma unroll
        for (int ks = 0; ks < 2; ++ks) {
            sh8 pa = *(const sh8*)(&Plds[w][lo][ks * 32 + hi * 8]);
            #pragma unroll
            for (int j2 = 0; j2 < 2; ++j2) {
                sh8 vb = *(const sh8*)(vT_eh + (long)(j2 * 16 + lo) * N_ + kc + ks * 32 + hi * 8);
                acc[j2] = MFMA16(pa, vb, acc[j2], 0, 0, 0);
            }
        }
    }
    #pragma unroll
    for (int j2 = 0; j2 < 2; ++j2)
        #pragma unroll
        for (int r = 0; r < 4; ++r) {
            long row = (long)e * N_ + n0 + w * 16 + hi * 4 + r;
            obuf[row * D_ + h * 32 + j2 * 16 + lo] = __float2bfloat16(acc[j2][r] / l[r]);
        }
}

// ---------------------------------------------------------------------------
// Flash cross-attention v2: grid (N/64, CCH=8, E). 8 key chunks of 768.
// K-tile staged in LDS; partials written normalized bf16 + (m,l).
// ---------------------------------------------------------------------------
__global__ __launch_bounds__(256, 2)
void flash_cross(const bf16* __restrict__ tok, const bf16* __restrict__ tokT,
                 bf16* __restrict__ Opart, float2* __restrict__ ml)
{
    const int e = blockIdx.z, ch = blockIdx.y;
    const int n0 = blockIdx.x * 64;
    const int tid = threadIdx.x, lane = tid & 63, w = tid >> 6;
    const int lo = lane & 15, hi = lane >> 4;
    const float scaleD = 1.0f / 16.0f;
    __shared__ bf16 Kt[64 * 256];
    __shared__ bf16 Plds[4][16][64];

    sh8 qf[8];
    {
        const bf16* qr = tok + ((long)e * N_ + n0 + w * 16 + lo) * D_;
        #pragma unroll
        for (int ks = 0; ks < 8; ++ks) qf[ks] = *(const sh8*)(qr + ks * 32 + hi * 8);
    }
    float m[4], l[4];
    fx4 acc[16] = {};
    #pragma unroll
    for (int r = 0; r < 4; ++r) { m[r] = -INFINITY; l[r] = 0.f; }

    for (int kc = ch * 768; kc < ch * 768 + 768; kc += 64) {
        const int seg = kc >> 11;
        const int src = (seg < e) ? seg : seg + 1;
        const int rowb = kc & 2047;
        stage_k64(tok + ((long)src * N_ + rowb) * D_, Kt, tid);
        asm volatile("s_waitcnt vmcnt(0)" ::: "memory");
        __syncthreads();

        float sv[4][4], rmax[4], rsum[4];
        #pragma unroll
        for (int j = 0; j < 4; ++j) {
            int krow = j * 16 + lo;
            fx4 s = {};
            #pragma unroll
            for (int ks = 0; ks < 8; ++ks) {
                sh8 kf = ldsK(Kt, krow, ks, hi);
                s = MFMA16(qf[ks], kf, s, 0, 0, 0);
            }
            #pragma unroll
            for (int r = 0; r < 4; ++r) sv[j][r] = s[r] * scaleD;
        }
        #pragma unroll
        for (int r = 0; r < 4; ++r)
            rmax[r] = fmaxf(fmaxf(sv[0][r], sv[1][r]), fmaxf(sv[2][r], sv[3][r]));
        #pragma unroll
        for (int d = 1; d < 16; d <<= 1)
            #pragma unroll
            for (int r = 0; r < 4; ++r) rmax[r] = fmaxf(rmax[r], __shfl_xor(rmax[r], d, 64));
        float sc[4];
        #pragma unroll
        for (int r = 0; r < 4; ++r) {
            float mn = fmaxf(m[r], rmax[r]);
            sc[r] = __expf(m[r] - mn);
            m[r] = mn; rsum[r] = 0.f;
        }
        #pragma unroll
        for (int j = 0; j < 4; ++j)
            #pragma unroll
            for (int r = 0; r < 4; ++r) {
                float p = __expf(sv[j][r] - m[r]);
                sv[j][r] = p; rsum[r] += p;
            }
        #pragma unroll
        for (int d = 1; d < 16; d <<= 1)
            #pragma unroll
            for (int r = 0; r < 4; ++r) rsum[r] += __shfl_xor(rsum[r], d, 64);
        #pragma unroll
        for (int r = 0; r < 4; ++r) l[r] = l[r] * sc[r] + rsum[r];
        #pragma unroll
        for (int j2 = 0; j2 < 16; ++j2)
            #pragma unroll
            for (int r = 0; r < 4; ++r) acc[j2][r] *= sc[r];
        #pragma unroll
        for (int j = 0; j < 4; ++j)
            #pragma unroll
            for (int r = 0; r < 4; ++r)
                Plds[w][hi * 4 + r][j * 16 + lo] = __float2bfloat16(sv[j][r]);
        asm volatile("s_waitcnt lgkmcnt(0)" ::: "memory");
        __builtin_amdgcn_sched_barrier(0);
        #pragma unroll
        for (int ks = 0; ks < 2; ++ks) {
            sh8 pa = *(const sh8*)(&Plds[w][lo][ks * 32 + hi * 8]);
            #pragma unroll
            for (int j2 = 0; j2 < 16; ++j2) {
                sh8 vb = *(const sh8*)(tokT + ((long)src * D_ + j2 * 16 + lo) * N_
                                       + rowb + ks * 32 + hi * 8);
                acc[j2] = MFMA16(pa, vb, acc[j2], 0, 0, 0);
            }
        }
        __syncthreads();
    }
    const long base = (long)ch * E_ * N_ + (long)e * N_ + n0 + w * 16;
    #pragma unroll
    for (int j2 = 0; j2 < 16; ++j2)
        #pragma unroll
        for (int r = 0; r < 4; ++r)
            Opart[(base + hi * 4 + r) * D_ + j2 * 16 + lo] = __float2bfloat16(acc[j2][r] / l[r]);
    if (lo == 0) {
        #pragma unroll
        for (int r = 0; r < 4; ++r) {
            float2 t; t.x = m[r]; t.y = l[r];
            ml[base + hi * 4 + r] = t;
        }
    }
}

// Merge 8 chunk-partials + token residual.
__global__ void cross_merge(const bf16* __restrict__ Opart, const float2* __restrict__ ml,
                            const float* __restrict__ tokens,
                            float* __restrict__ x0f, bf16* __restrict__ x0bf)
{
    long row = blockIdx.x; int d = threadIdx.x;
    float2 v[CCH];
    float mx = -INFINITY;
    #pragma unroll
    for (int i = 0; i < CCH; ++i) { v[i] = ml[(long)i * E_ * N_ + row]; mx = fmaxf(mx, v[i].x); }
    float L = 0.f, o = 0.f;
    #pragma unroll
    for (int i = 0; i < CCH; ++i) {
        float wgt = v[i].y * __expf(v[i].x - mx);
        L += wgt;
        o += wgt * __bfloat162float(Opart[((long)i * E_ * N_ + row) * D_ + d]);
    }
    float val = tokens[row * D_ + d] + o / L;
    x0f[row * D_ + d] = val;
    x0bf[row * D_ + d] = __float2bfloat16(val);
}

// ---------------------------------------------------------------------------
// ret_flash: per (q-tile, layer, e*2+mhalf). O[e,l] += exp(x2@mem^T/16) @ maggT^T,
// rs[e,l] += rowsum. No max subtraction (scores ~ N(0,1)). Atomic f32 merge of 2 halves.
// ---------------------------------------------------------------------------
__global__ __launch_bounds__(256, 2)
void ret_flash(const bf16* __restrict__ x2b, const bf16* __restrict__ memb,
               const bf16* __restrict__ maggT, float* __restrict__ Omem,
               float* __restrict__ rsbuf)
{
    const int li = blockIdx.y;
    const int e = blockIdx.z >> 1, mh = blockIdx.z & 1;
    const int n0 = blockIdx.x * 64;
    const int tid = threadIdx.x, lane = tid & 63, w = tid >> 6;
    const int lo = lane & 15, hi = lane >> 4;
    const float scaleD = 1.0f / 16.0f;
    __shared__ bf16 Kt[64 * 256];
    __shared__ bf16 Plds[4][16][64];

    sh8 qf[8];
    {
        const bf16* qr = x2b + ((long)e * N_ + n0 + w * 16 + lo) * D_;
        #pragma unroll
        for (int ks = 0; ks < 8; ++ks) qf[ks] = *(const sh8*)(qr + ks * 32 + hi * 8);
    }
    float l[4] = {0.f, 0.f, 0.f, 0.f};
    fx4 acc[16] = {};
    const bf16* Kl = memb + (long)li * M_ * D_;
    const bf16* Vl = maggT + (long)li * D_ * M_;

    for (int m0 = mh * 2048; m0 < mh * 2048 + 2048; m0 += 64) {
        stage_k64(Kl + (long)m0 * D_, Kt, tid);
        asm volatile("s_waitcnt vmcnt(0)" ::: "memory");
        __syncthreads();

        float sv[4][4], rsum[4] = {0.f, 0.f, 0.f, 0.f};
        #pragma unroll
        for (int j = 0; j < 4; ++j) {
            int krow = j * 16 + lo;
            fx4 s = {};
            #pragma unroll
            for (int ks = 0; ks < 8; ++ks) {
                sh8 kf = ldsK(Kt, krow, ks, hi);
                s = MFMA16(qf[ks], kf, s, 0, 0, 0);
            }
            #pragma unroll
            for (int r = 0; r < 4; ++r) {
                float p = __expf(s[r] * scaleD);
                sv[j][r] = p; rsum[r] += p;
            }
        }
        #pragma unroll
        for (int d = 1; d < 16; d <<= 1)
            #pragma unroll
            for (int r = 0; r < 4; ++r) rsum[r] += __shfl_xor(rsum[r], d, 64);
        #pragma unroll
        for (int r = 0; r < 4; ++r) l[r] += rsum[r];
        #pragma unroll
        for (int j = 0; j < 4; ++j)
            #pragma unroll
            for (int r = 0; r < 4; ++r)
                Plds[w][hi * 4 + r][j * 16 + lo] = __float2bfloat16(sv[j][r]);
        asm volatile("s_waitcnt lgkmcnt(0)" ::: "memory");
        __builtin_amdgcn_sched_barrier(0);
        #pragma unroll
        for (int ks = 0; ks < 2; ++ks) {
            sh8 pa = *(const sh8*)(&Plds[w][lo][ks * 32 + hi * 8]);
            #pragma unroll
            for (int j2 = 0; j2 < 16; ++j2) {
                sh8 vb = *(const sh8*)(Vl + (long)(j2 * 16 + lo) * M_ + m0 + ks * 32 + hi * 8);
                acc[j2] = MFMA16(pa, vb, acc[j2], 0, 0, 0);
            }
        }
        __syncthreads();
    }
    const long rowb = ((long)(e * L_ + li)) * N_ + n0 + w * 16;
    #pragma unroll
    for (int j2 = 0; j2 < 16; ++j2)
        #pragma unroll
        for (int r = 0; r < 4; ++r)
            atomicAdd(&Omem[(rowb + hi * 4 + r) * D_ + j2 * 16 + lo], acc[j2][r]);
    if (lo == 0) {
        #pragma unroll
        for (int r = 0; r < 4; ++r)
            atomicAdd(&rsbuf[rowb + hi * 4 + r], l[r]);
    }
}

// ---------------------------------------------------------------------------
// upd_flash: per (m-tile, layer, e). updsum[l] += (exp(mem@x2^T/16)/rs) @ x2.
// ---------------------------------------------------------------------------
__global__ __launch_bounds__(256, 2)
void upd_flash(const bf16* __restrict__ x2b, const bf16* __restrict__ memb,
               const bf16* __restrict__ x2T, const float* __restrict__ rsbuf,
               float* __restrict__ updsum)
{
    const int li = blockIdx.y, e = blockIdx.z;
    const int m0 = blockIdx.x * 64;
    const int tid = threadIdx.x, lane = tid & 63, w = tid >> 6;
    const int lo = lane & 15, hi = lane >> 4;
    const float scaleD = 1.0f / 16.0f;
    __shared__ bf16 Kt[64 * 256];
    __shared__ bf16 Plds[4][16][64];

    sh8 qf[8];
    {
        const bf16* qr = memb + (long)li * M_ * D_ + (long)(m0 + w * 16 + lo) * D_;
        #pragma unroll
        for (int ks = 0; ks < 8; ++ks) qf[ks] = *(const sh8*)(qr + ks * 32 + hi * 8);
    }
    fx4 acc[16] = {};
    const float* rse = rsbuf + (long)(e * L_ + li) * N_;
    const bf16* x2Te = x2T + (long)e * D_ * N_;

    for (int n0 = 0; n0 < N_; n0 += 64) {
        stage_k64(x2b + ((long)e * N_ + n0) * D_, Kt, tid);
        float rinv[4];
        #pragma unroll
        for (int j = 0; j < 4; ++j) rinv[j] = 1.0f / rse[n0 + j * 16 + lo];
        asm volatile("s_waitcnt vmcnt(0)" ::: "memory");
        __syncthreads();

        #pragma unroll
        for (int j = 0; j < 4; ++j) {
            int krow = j * 16 + lo;
            fx4 s = {};
            #pragma unroll
            for (int ks = 0; ks < 8; ++ks) {
                sh8 kf = ldsK(Kt, krow, ks, hi);
                s = MFMA16(qf[ks], kf, s, 0, 0, 0);
            }
            #pragma unroll
            for (int r = 0; r < 4; ++r) {
                float p = __expf(s[r] * scaleD) * rinv[j];
                Plds[w][hi * 4 + r][j * 16 + lo] = __float2bfloat16(p);
            }
        }
        asm volatile("s_waitcnt lgkmcnt(0)" ::: "memory");
        __builtin_amdgcn_sched_barrier(0);
        #pragma unroll
        for (int ks = 0; ks < 2; ++ks) {
            sh8 pa = *(const sh8*)(&Plds[w][lo][ks * 32 + hi * 8]);
            #pragma unroll
            for (int j2 = 0; j2 < 16; ++j2) {
                sh8 vb = *(const sh8*)(x2Te + (long)(j2 * 16 + lo) * N_ + n0 + ks * 32 + hi * 8);
                acc[j2] = MFMA16(pa, vb, acc[j2], 0, 0, 0);
            }
        }
        __syncthreads();
    }
    const long mrow = (long)li * M_ + m0 + w * 16;
    #pragma unroll
    for (int j2 = 0; j2 < 16; ++j2)
        #pragma unroll
        for (int r = 0; r < 4; ++r)
            atomicAdd(&updsum[(mrow + hi * 4 + r) * D_ + j2 * 16 + lo], acc[j2][r]);
}

// xfinal[e,n] += sum_l Omem[e,l,n]/rs[e,l,n] + agg_b
__global__ void retscale(const float* __restrict__ Omem, const float* __restrict__ rsbuf,
                         const float* __restrict__ aggb, float* __restrict__ xfinal)
{
    long row = blockIdx.x; int d = threadIdx.x;
    int e = (int)(row >> 11); long n = row & 2047;
    float s = aggb[d];
    #pragma unroll
    for (int li = 0; li < L_; ++li) {
        long rr = ((long)(e * L_ + li)) * N_ + n;
        s += Omem[rr * D_ + d] / rsbuf[rr];
    }
    xfinal[row * D_ + d] += s;
}

// LayerNorm over D=256, per-expert weights (expert = row>>11). f32 + bf16 out.
__global__ void layernorm_rows(const float* __restrict__ X, const float* __restrict__ g,
                               const float* __restrict__ b, float* __restrict__ out,
                               bf16* __restrict__ outbf)
{
    __shared__ float red[256];
    int row = blockIdx.x, t = threadIdx.x;
    int e = row >> 11;
    float v = X[(long)row * 256 + t];
    red[t] = v; __syncthreads();
    for (int s = 128; s > 0; s >>= 1) { if (t < s) red[t] += red[t + s]; __syncthreads(); }
    float mu = red[0] * (1.0f / 256.0f); __syncthreads();
    float d = v - mu;
    red[t] = d * d; __syncthreads();
    for (int s = 128; s > 0; s >>= 1) { if (t < s) red[t] += red[t + s]; __syncthreads(); }
    float var = red[0] * (1.0f / 256.0f);
    float o = d * rsqrtf(var + EPS_) * g[e * 256 + t] + b[e * 256 + t];
    out[(long)row * 256 + t] = o;
    outbf[(long)row * 256 + t] = __float2bfloat16(o);
}

__global__ void cvt_bf16(const float* __restrict__ in, bf16* __restrict__ out, long n) {
    long i = ((long)blockIdx.x * 256 + threadIdx.x) * 4;
    if (i < n) {
        float4 v = *(const float4*)(in + i);
        out[i + 0] = __float2bfloat16(v.x);
        out[i + 1] = __float2bfloat16(v.y);
        out[i + 2] = __float2bfloat16(v.z);
        out[i + 3] = __float2bfloat16(v.w);
    }
}

__device__ inline float ldf(const float* p) { return *p; }
__device__ inline float ldf(const bf16* p)  { return __bfloat162float(*p); }

template<typename T>
__global__ void transpose_bf16(const T* __restrict__ in, bf16* __restrict__ out,
                               int R, int C, int ldin, int ldout) {
    __shared__ float t[64][65];
    int tx = threadIdx.x & 63, ty = threadIdx.x >> 6;
    int r0 = blockIdx.y * 64, c0 = blockIdx.x * 64;
    #pragma unroll
    for (int i = 0; i < 16; ++i) {
        int r = ty + i * 4;
        t[r][tx] = ldf(&in[(long)(r0 + r) * ldin + (c0 + tx)]);
    }
    __syncthreads();
    #pragma unroll
    for (int i = 0; i < 16; ++i) {
        int c = ty + i * 4;
        out[(long)(c0 + c) * ldout + (r0 + tx)] = __float2bfloat16(t[tx][c]);
    }
}

__global__ void mem_update(const float* __restrict__ mem, const float* __restrict__ upd,
                           float* __restrict__ out) {
    long i = (long)blockIdx.x * 256 + threadIdx.x;
    if (i < (long)L_ * M_ * D_) out[i] = (1.0f - GAMMA_) * mem[i] + GAMMA_ * upd[i];
}

__global__ void pool_partial(const float* __restrict__ xf, float* __restrict__ pooled) {
    int e = blockIdx.x, chunk = blockIdx.y, t = threadIdx.x;
    float s = 0.f;
    int n0 = chunk * (N_ / 16);
    for (int n = n0; n < n0 + N_ / 16; ++n)
        s += xf[((long)e * N_ + n) * D_ + t];
    atomicAdd(&pooled[e * D_ + t], s * (1.0f / (float)N_));
}

__global__ void gate_kernel(const float* __restrict__ pooled, const float* __restrict__ gg,
                            float* __restrict__ out_gate, float* __restrict__ ws_gate) {
    __shared__ float red[256];
    __shared__ float logits[4];
    int t = threadIdx.x;
    for (int e = 0; e < 4; ++e) {
        red[t] = pooled[e * 256 + t] * gg[t];
        __syncthreads();
        for (int s = 128; s > 0; s >>= 1) { if (t < s) red[t] += red[t + s]; __syncthreads(); }
        if (t == 0) logits[e] = red[0];
        __syncthreads();
    }
    if (t == 0) {
        float mm = fmaxf(fmaxf(logits[0], logits[1]), fmaxf(logits[2], logits[3]));
        float g[4]; float s = 0.f;
        for (int e = 0; e < 4; ++e) { g[e] = __expf(logits[e] - mm); s += g[e]; }
        for (int e = 0; e < 4; ++e) {
            float w = g[e] / s;
            out_gate[e] = w;
            ws_gate[e] = w;
        }
    }
}

__global__ void fuse_kernel(const float* __restrict__ xf, const float* __restrict__ g4,
                            float* __restrict__ out) {
    long i = (long)blockIdx.x * 256 + threadIdx.x;
    const long ND = (long)N_ * D_;
    if (i < ND)
        out[i] = g4[0] * xf[i] + g4[1] * xf[ND + i] + g4[2] * xf[2 * ND + i] + g4[3] * xf[3 * ND + i];
}

// ---------------------------------------------------------------------------

static void gemm(hipStream_t s, int BN, const bf16* A, int lda, const bf16* Bt, int ldb,
                 long wstride, float* C, int ldc, bf16* Cbf, int M, int N, int K, int Kc,
                 float alpha, const float* bias, long bstride, const float* res, int ldres,
                 int flags, const bf16* zb) {
    dim3 g((N + BN - 1) / BN, (M + 127) / 128, (K + Kc - 1) / Kc);
    if (BN == 128)
        gemm_bf16<128><<<g, dim3(256), 0, s>>>(A, lda, Bt, ldb, wstride, C, ldc, Cbf, M, N, K, Kc,
                                               alpha, bias, bstride, res, ldres, flags, zb);
    else
        gemm_bf16<64><<<g, dim3(256), 0, s>>>(A, lda, Bt, ldb, wstride, C, ldc, Cbf, M, N, K, Kc,
                                              alpha, bias, bstride, res, ldres, flags, zb);
}

static void transposeF(hipStream_t s, const float* in, bf16* out, int R, int C, int ldin, int ldout) {
    transpose_bf16<float><<<dim3(C / 64, R / 64), dim3(256), 0, s>>>(in, out, R, C, ldin, ldout);
}
static void transposeB(hipStream_t s, const bf16* in, bf16* out, int R, int C, int ldin, int ldout) {
    transpose_bf16<bf16><<<dim3(C / 64, R / 64), dim3(256), 0, s>>>(in, out, R, C, ldin, ldout);
}
static void convert(hipStream_t s, const float* in, bf16* out, long n) {
    cvt_bf16<<<dim3((unsigned)((n / 4 + 255) / 256)), dim3(256), 0, s>>>(in, out, n);
}

extern "C" void kernel_launch(void* const* d_in, const int* in_sizes, int n_in,
                              void* d_out, int out_size, void* d_ws, size_t ws_size,
                              hipStream_t stream) {
    const float* tokens    = (const float*)d_in[0];
    const float* memories  = (const float*)d_in[1];
    const float* in_proj_w = (const float*)d_in[2];
    const float* in_proj_b = (const float*)d_in[3];
    const float* out_w     = (const float*)d_in[4];
    const float* out_b     = (const float*)d_in[5];
    const float* lin1_w    = (const float*)d_in[6];
    const float* lin1_b    = (const float*)d_in[7];
    const float* lin2_w    = (const float*)d_in[8];
    const float* lin2_b    = (const float*)d_in[9];
    const float* ln1_w     = (const float*)d_in[10];
    const float* ln1_b     = (const float*)d_in[11];
    const float* ln2_w     = (const float*)d_in[12];
    const float* ln2_b     = (const float*)d_in[13];
    const float* agg_w     = (const float*)d_in[14];
    const float* agg_b     = (const float*)d_in[15];
    const float* gg        = (const float*)d_in[16];

    char* p = (char*)d_ws;
    auto alloc = [&](size_t bytes) { char* r = p; p += (bytes + 255) & ~(size_t)255; return r; };

    // region0 (32MB), time-shared: Opart(bf16, cross) -> hid_all(FFN) -> Omem(f32, mem)
    char*  region0 = alloc((size_t)32 * 1024 * 1024);
    bf16*  Opart   = (bf16*)region0;                    // [8][E*N][256] bf16 = 32MB
    bf16*  hid_all = (bf16*)region0;                    // [8192][2048] bf16 = 32MB
    float* Omem    = (float*)region0;                   // [12][2048][256] f32 = 25.2MB

    float* updsum  = (float*)alloc((size_t)L_ * M_ * D_ * 4);
    float* xfinal  = (float*)alloc((size_t)E_ * N_ * D_ * 4);
    bf16*  x2_bf   = (bf16*)alloc((size_t)E_ * N_ * D_ * 2);
    bf16*  x2T_bf  = (bf16*)alloc((size_t)E_ * D_ * N_ * 2);
    float* x0f     = (float*)alloc((size_t)E_ * N_ * D_ * 4);
    bf16*  x0bf    = (bf16*)alloc((size_t)E_ * N_ * D_ * 2);
    float* ybuf    = (float*)alloc((size_t)E_ * N_ * D_ * 4);
    bf16*  obuf_bf = (bf16*)alloc((size_t)E_ * N_ * D_ * 2);
    bf16*  qkv_bf  = (bf16*)alloc((size_t)E_ * N_ * 3 * D_ * 2);
    bf16*  vT_bf   = (bf16*)alloc((size_t)E_ * D_ * N_ * 2);
    bf16*  tok_bf  = (bf16*)alloc((size_t)E_ * N_ * D_ * 2);
    bf16*  tokT_bf = (bf16*)alloc((size_t)E_ * D_ * N_ * 2);
    bf16*  mem_bf  = (bf16*)alloc((size_t)L_ * M_ * D_ * 2);
    bf16*  maggT   = (bf16*)alloc((size_t)L_ * D_ * M_ * 2);
    float2* mlbuf  = (float2*)alloc((size_t)CCH * E_ * N_ * sizeof(float2));
    float* rsbuf   = (float*)alloc((size_t)E_ * L_ * N_ * 4);
    bf16*  ipw_bf  = (bf16*)alloc((size_t)E_ * 3 * D_ * D_ * 2);
    bf16*  outw_bf = (bf16*)alloc((size_t)E_ * D_ * D_ * 2);
    bf16*  l1w_bf  = (bf16*)alloc((size_t)E_ * F_ * D_ * 2);
    bf16*  l2w_bf  = (bf16*)alloc((size_t)E_ * D_ * F_ * 2);
    bf16*  aggw_bf = (bf16*)alloc((size_t)D_ * 3 * D_ * 2);
    float* pooled  = (float*)alloc(1024 * 4);
    float* gatebuf = (float*)alloc(64);
    bf16*  zerobuf = (bf16*)alloc(64);

    float* x1f  = x0f;
    bf16*  x1bf = x0bf;

    float* out_fused = (float*)d_out;
    float* out_gate  = out_fused + (long)N_ * D_;
    float* out_mem   = out_gate + E_;

    hipMemsetAsync(zerobuf, 0, 64, stream);
    hipMemsetAsync(pooled, 0, 1024 * 4, stream);
    hipMemsetAsync(updsum, 0, (size_t)L_ * M_ * D_ * 4, stream);

    // one-time conversions / transposes
    convert(stream, tokens, tok_bf, (long)E_ * N_ * D_);
    convert(stream, memories, mem_bf, (long)L_ * M_ * D_);
    convert(stream, in_proj_w, ipw_bf, (long)E_ * 3 * D_ * D_);
    convert(stream, out_w, outw_bf, (long)E_ * D_ * D_);
    convert(stream, lin1_w, l1w_bf, (long)E_ * F_ * D_);
    convert(stream, lin2_w, l2w_bf, (long)E_ * D_ * F_);
    convert(stream, agg_w, aggw_bf, (long)D_ * 3 * D_);
    for (int e = 0; e < E_; ++e)
        transposeF(stream, tokens + (long)e * N_ * D_, tokT_bf + (long)e * D_ * N_, N_, D_, D_, N_);
    // maggT_l = agg_w_l @ mem_l^T : [256, 4096]
    for (int l = 0; l < L_; ++l)
        gemm(stream, 128, aggw_bf + l * D_, 3 * D_, mem_bf + (long)l * M_ * D_, D_, 0,
             nullptr, M_, maggT + (long)l * D_ * M_, D_, M_, D_, D_,
             1.0f, nullptr, 0, nullptr, 0, 0, zerobuf);

    // ---- cross-expert attention ----
    flash_cross<<<dim3(N_ / 64, CCH, E_), dim3(256), 0, stream>>>(tok_bf, tokT_bf, Opart, mlbuf);
    cross_merge<<<dim3(E_ * N_), dim3(256), 0, stream>>>(Opart, mlbuf, tokens, x0f, x0bf);

    // ---- MHA (batched) ----
    gemm(stream, 128, x0bf, D_, ipw_bf, D_, (long)3 * D_ * D_,
         nullptr, 3 * D_, qkv_bf, E_ * N_, 3 * D_, D_, D_,
         1.0f, in_proj_b, 3 * D_, nullptr, 0, 0, zerobuf);
    for (int e = 0; e < E_; ++e)
        transposeB(stream, qkv_bf + (long)e * N_ * 3 * D_ + 2 * D_, vT_bf + (long)e * D_ * N_,
                   N_, D_, 3 * D_, N_);
    flash_mha<<<dim3(N_ / 64, H_, E_), dim3(256), 0, stream>>>(qkv_bf, vT_bf, obuf_bf);
    gemm(stream, 64, obuf_bf, D_, outw_bf, D_, (long)D_ * D_,
         ybuf, D_, nullptr, E_ * N_, D_, D_, D_,
         1.0f, out_b, D_, x0f, D_, 0, zerobuf);
    layernorm_rows<<<dim3(E_ * N_), dim3(256), 0, stream>>>(ybuf, ln1_w, ln1_b, x1f, x1bf);

    // ---- FFN (batched) ----
    gemm(stream, 128, x1bf, D_, l1w_bf, D_, (long)F_ * D_,
         nullptr, F_, hid_all, E_ * N_, F_, D_, D_,
         1.0f, lin1_b, F_, nullptr, 0, GF_RELU, zerobuf);
    hipMemsetAsync(ybuf, 0, (size_t)E_ * N_ * D_ * 4, stream);
    gemm(stream, 64, hid_all, F_, l2w_bf, F_, (long)D_ * F_,
         ybuf, D_, nullptr, E_ * N_, D_, F_, 512,
         1.0f, lin2_b, D_, x1f, D_, GF_ATOMIC, zerobuf);
    layernorm_rows<<<dim3(E_ * N_), dim3(256), 0, stream>>>(ybuf, ln2_w, ln2_b, xfinal, x2_bf);
    for (int e = 0; e < E_; ++e)
        transposeF(stream, xfinal + (long)e * N_ * D_, x2T_bf + (long)e * D_ * N_, N_, D_, D_, N_);

    // ---- memory read/write (flash, no-max softmax) ----
    hipMemsetAsync(Omem, 0, (size_t)E_ * L_ * N_ * D_ * 4, stream);
    hipMemsetAsync(rsbuf, 0, (size_t)E_ * L_ * N_ * 4, stream);
    ret_flash<<<dim3(N_ / 64, L_, E_ * 2), dim3(256), 0, stream>>>(x2_bf, mem_bf, maggT, Omem, rsbuf);
    upd_flash<<<dim3(M_ / 64, L_, E_), dim3(256), 0, stream>>>(x2_bf, mem_bf, x2T_bf, rsbuf, updsum);
    retscale<<<dim3(E_ * N_), dim3(256), 0, stream>>>(Omem, rsbuf, agg_b, xfinal);

    mem_update<<<dim3((L_ * M_ * D_ + 255) / 256), dim3(256), 0, stream>>>(memories, updsum, out_mem);
    pool_partial<<<dim3(E_, 16), dim3(256), 0, stream>>>(xfinal, pooled);
    gate_kernel<<<dim3(1), dim3(256), 0, stream>>>(pooled, gg, out_gate, gatebuf);
    fuse_kernel<<<dim3((N_ * D_ + 255) / 256), dim3(256), 0, stream>>>(xfinal, gatebuf, out_fused);
}